// Round 3
// baseline (288.547 us; speedup 1.0000x reference)
//
#include <hip/hip_runtime.h>
#include <hip/hip_bf16.h>

typedef __attribute__((ext_vector_type(8))) short short8v;   // 8 bf16
typedef __attribute__((ext_vector_type(4))) float f32x4;
typedef __attribute__((ext_vector_type(4))) int int4v;

#define NTOK  2048
#define NEMBD 768
#define DFF   3072
#define NEXP  8
#define MAXSLOT 5120          // 128-aligned per-expert regions, sum <= 4992
#define NT1 24                // DFF/128
#define NT2 6                 // NEMBD/128
#define MAXT1 40              // max 128-row tiles (bound 39)
#define MAXT2 80              // max 64-row tiles (bound 78)

// ---- workspace layout (bytes) ----
#define WS_XBF   0                                   // ushort [2048][768]
#define WS_GATES (WS_XBF + (size_t)NTOK*NEMBD*2)     // float  [2048][8]
#define WS_TE    (WS_GATES + NTOK*8*4)               // int    [2048][2]
#define WS_TW    (WS_TE + NTOK*2*4)                  // float  [2048][2]
#define WS_KL    (WS_TW + NTOK*2*4)                  // float  [2048]
#define WS_CTRL  (WS_KL + NTOK*4)                    // int[512]
#define WS_STOK  (WS_CTRL + 2048)                    // int    [MAXSLOT]
#define WS_SGATE (WS_STOK + MAXSLOT*4)               // float  [MAXSLOT]
#define WS_WFCT  (WS_SGATE + MAXSLOT*4)              // ushort [8][3072][768]
#define WS_WPT   (WS_WFCT + (size_t)NEXP*DFF*NEMBD*2)// ushort [8][768][3072]
#define WS_H     (WS_WPT + (size_t)NEXP*NEMBD*DFF*2) // ushort [MAXSLOT][3072]

__device__ __forceinline__ unsigned short f2bf(float f) {
    union { float f; unsigned u; } v; v.f = f;
    unsigned r = v.u + 0x7fffu + ((v.u >> 16) & 1u);   // RNE
    return (unsigned short)(r >> 16);
}

__device__ __forceinline__ void gload16(const void* g, void* l) {
    __builtin_amdgcn_global_load_lds(
        (const __attribute__((address_space(1))) void*)g,
        (__attribute__((address_space(3))) void*)l, 16, 0, 0);
}

// ---------------- router: wave-parallel logits/softmax/top2/KL + x->bf16 ----------------
// 512 blocks x 4 waves; one wave per token. lane: e = lane&7, kg = lane>>3.
__global__ __launch_bounds__(256) void k_router(
    const float* __restrict__ x, const float* __restrict__ WgP, const float* __restrict__ WgQ,
    unsigned short* __restrict__ xbf, float* __restrict__ gates,
    int* __restrict__ te, float* __restrict__ tw, float* __restrict__ kl_tok,
    int* __restrict__ ctrl)
{
    int tid = threadIdx.x, wave = tid >> 6, lane = tid & 63;
    int t = blockIdx.x * 4 + wave;
    int b = t >> 10, l = t & 1023;
    int lf = l + 2; if (lf > 1023) lf = 1023;           // lookforward pad-with-last
    const float* xr = x + (size_t)t * NEMBD;
    const float* xf = x + (size_t)((b << 10) + lf) * NEMBD;
    int e = lane & 7, kg = lane >> 3;

    float accP = 0.f, accQ = 0.f;
    #pragma unroll 8
    for (int i = 0; i < 96; ++i) {
        int k = kg + 8 * i;
        // W addr = k*8+e = lane + 64*i  -> fully coalesced
        accP += xr[k] * WgP[k * NEXP + e];
        accQ += xf[k] * WgQ[k * NEXP + e];
    }
    // reduce over kg (lane bits 3..5)
    #pragma unroll
    for (int off = 8; off < 64; off <<= 1) {
        accP += __shfl_xor(accP, off);
        accQ += __shfl_xor(accQ, off);
    }
    // softmax over experts (lane bits 0..2); every lane redundantly computes
    float mq = accQ, mp = accP;
    #pragma unroll
    for (int off = 1; off < 8; off <<= 1) {
        mq = fmaxf(mq, __shfl_xor(mq, off));
        mp = fmaxf(mp, __shfl_xor(mp, off));
    }
    float gq = __expf(accQ - mq), gp = __expf(accP - mp);
    float se = gq, sp = gp;
    #pragma unroll
    for (int off = 1; off < 8; off <<= 1) {
        se += __shfl_xor(se, off);
        sp += __shfl_xor(sp, off);
    }
    // top-2 with lowest-index tie-break (matches lax.top_k)
    float v0 = gq; int e0 = e;
    #pragma unroll
    for (int off = 1; off < 8; off <<= 1) {
        float ov = __shfl_xor(v0, off); int oe = __shfl_xor(e0, off);
        if (ov > v0 || (ov == v0 && oe < e0)) { v0 = ov; e0 = oe; }
    }
    float vx = (e == e0) ? -1.f : gq;    // gq > 0, so -1 acts as -inf
    float v1 = vx; int e1 = e;
    #pragma unroll
    for (int off = 1; off < 8; off <<= 1) {
        float ov = __shfl_xor(v1, off); int oe = __shfl_xor(e1, off);
        if (ov > v1 || (ov == v1 && oe < e1)) { v1 = ov; e1 = oe; }
    }
    // KL(post || prior) summed over experts
    float lq = (accQ - mq) - logf(se);
    float lp = (accP - mp) - logf(sp);
    float kl = __expf(lq) * (lq - lp);
    #pragma unroll
    for (int off = 1; off < 8; off <<= 1) kl += __shfl_xor(kl, off);

    if (lane < 8) gates[t * NEXP + e] = gq / se;
    if (lane == 0) {
        float s2 = v0 + v1;
        te[t * 2] = e0; te[t * 2 + 1] = e1;
        tw[t * 2] = v0 / s2; tw[t * 2 + 1] = v1 / s2;
        atomicAdd(&ctrl[e0], 1); atomicAdd(&ctrl[e1], 1);
        kl_tok[t] = kl;
    }

    // x -> bf16 for this block's 4 token rows
    const float4* xs4 = (const float4*)(x + (size_t)blockIdx.x * 4 * NEMBD);
    ushort4* xd4 = (ushort4*)(xbf + (size_t)blockIdx.x * 4 * NEMBD);
    for (int i = tid; i < 4 * NEMBD / 4; i += 256) {
        float4 v = xs4[i];
        ushort4 o;
        o.x = f2bf(v.x); o.y = f2bf(v.y); o.z = f2bf(v.z); o.w = f2bf(v.w);
        xd4[i] = o;
    }
}

// ---------------- transpose+convert both weights: in [E][R][C] f32 -> out [E][C][R] bf16 ----
__global__ __launch_bounds__(256) void k_transpose(
    const float* __restrict__ inA, unsigned short* __restrict__ outA,   // W_fc
    const float* __restrict__ inB, unsigned short* __restrict__ outB)   // W_proj
{
    int bx = blockIdx.x;
    const float* in; unsigned short* out; int R, C, tilesC;
    if (bx < NEXP * 12 * 48) { in = inA; out = outA; R = NEMBD; C = DFF; tilesC = 48; }
    else { bx -= NEXP * 12 * 48; in = inB; out = outB; R = DFF; C = NEMBD; tilesC = 12; }
    int per = (R >> 6) * tilesC;
    int e = bx / per, rem = bx % per;
    int rt = rem / tilesC, ct = rem % tilesC;
    __shared__ unsigned short sT[64][72];
    const float* src = in + ((size_t)e * R + rt * 64) * C + ct * 64;
    int tid = threadIdx.x;
    #pragma unroll
    for (int i = 0; i < 4; ++i) {
        int idx = tid + i * 256;
        int r = idx >> 4, c4 = idx & 15;
        float4 v = *(const float4*)&src[(size_t)r * C + c4 * 4];
        ushort4 o; o.x = f2bf(v.x); o.y = f2bf(v.y); o.z = f2bf(v.z); o.w = f2bf(v.w);
        *(ushort4*)&sT[r][c4 * 4] = o;
    }
    __syncthreads();
    unsigned short* dst = out + ((size_t)e * C + ct * 64) * R + rt * 64;
    #pragma unroll
    for (int i = 0; i < 2; ++i) {
        int idx = tid + i * 256;
        int oc = idx >> 3, j = idx & 7;
        unsigned short u[8];
        #pragma unroll
        for (int s = 0; s < 8; ++s) u[s] = sT[j * 8 + s][oc];
        *(int4v*)&dst[(size_t)oc * R + j * 8] = *(const int4v*)u;
    }
}

// ---------------- sched: offsets + tile tables + slot init + build (1 block) ----------------
// ctrl: [0..7] counts, [16..23] expert base, [24] total, [25] nt1, [26] nt2,
//       [64..103] t1 (e<<16|mt), [128..207] t2
__global__ __launch_bounds__(256) void k_sched(
    const int* __restrict__ te, const float* __restrict__ tw,
    int* __restrict__ ctrl, int* __restrict__ stok, float* __restrict__ sgate)
{
    __shared__ int cur[NEXP];
    int tid = threadIdx.x;
    if (tid == 0) {
        int off = 0, n1 = 0, n2 = 0;
        for (int e = 0; e < NEXP; ++e) {
            ctrl[16 + e] = off;
            int t128 = (ctrl[e] + 127) >> 7;
            for (int m = 0; m < t128; ++m)     ctrl[64 + n1++]  = (e << 16) | m;
            for (int m = 0; m < 2 * t128; ++m) ctrl[128 + n2++] = (e << 16) | m;
            off += t128 << 7;
        }
        ctrl[24] = off; ctrl[25] = n1; ctrl[26] = n2;
    }
    if (tid < NEXP) cur[tid] = 0;
    for (int i = tid; i < MAXSLOT; i += 256) { stok[i] = 0; sgate[i] = 0.f; }
    __syncthreads();
    for (int t = tid; t < NTOK; t += 256) {
        #pragma unroll
        for (int k = 0; k < 2; ++k) {
            int e = te[t * 2 + k];
            int s = atomicAdd(&cur[e], 1);
            int flat = ctrl[16 + e] + s;
            stok[flat] = t; sgate[flat] = tw[t * 2 + k];
        }
    }
}

// ---------------- GEMM1: H = relu(Xg @ WfcT^T)^2, 128x128 tile, BK=64 ----------------
__global__ __launch_bounds__(256) void k_gemm1(
    const unsigned short* __restrict__ xbf, const unsigned short* __restrict__ WfcT,
    const int* __restrict__ ctrl, const int* __restrict__ slot_tok,
    unsigned short* __restrict__ H)
{
    int bx = blockIdx.x;                      // grid = MAXT1*NT1 = 960
    int swz = (bx & 7) * (MAXT1 * NT1 / 8) + (bx >> 3);
    int nt = swz / MAXT1, tI = swz % MAXT1;
    if (tI >= ctrl[25]) return;
    int pk = ctrl[64 + tI];
    int e = pk >> 16, mt = pk & 0xffff;
    int base = ctrl[16 + e] + (mt << 7);

    __shared__ unsigned short sAB[2 * 128 * 64];   // sA | sB, reused as sC[128][128]
    unsigned short* sA = sAB;
    unsigned short* sB = sAB + 128 * 64;

    int tid = threadIdx.x, w = tid >> 6, lane = tid & 63;
    int wr = w >> 1, wc = w & 1;

    const unsigned short* wfc = WfcT + ((size_t)e * DFF + nt * 128) * NEMBD;
    const unsigned short* aptr[4]; const unsigned short* bptr[4];
    #pragma unroll
    for (int i = 0; i < 4; ++i) {
        int r = i * 32 + w * 8 + (lane >> 3);
        aptr[i] = xbf + (size_t)slot_tok[base + r] * NEMBD + (lane & 7) * 8;
        bptr[i] = wfc + (size_t)r * NEMBD + (lane & 7) * 8;
    }

    f32x4 acc[4][4];
    #pragma unroll
    for (int i = 0; i < 4; ++i)
        #pragma unroll
        for (int j = 0; j < 4; ++j) acc[i][j] = (f32x4){0.f, 0.f, 0.f, 0.f};

    for (int kk = 0; kk < NEMBD; kk += 64) {
        #pragma unroll
        for (int i = 0; i < 4; ++i) {
            gload16(aptr[i] + kk, &sA[(i * 256 + w * 64) * 8]);
            gload16(bptr[i] + kk, &sB[(i * 256 + w * 64) * 8]);
        }
        __syncthreads();
        #pragma unroll
        for (int kh = 0; kh < 2; ++kh) {
            short8v af[4], bfv[4];
            #pragma unroll
            for (int m = 0; m < 4; ++m)
                af[m] = *(const short8v*)&sA[(wr * 64 + m * 16 + (lane & 15)) * 64 + kh * 32 + (lane >> 4) * 8];
            #pragma unroll
            for (int n = 0; n < 4; ++n)
                bfv[n] = *(const short8v*)&sB[(wc * 64 + n * 16 + (lane & 15)) * 64 + kh * 32 + (lane >> 4) * 8];
            #pragma unroll
            for (int m = 0; m < 4; ++m)
                #pragma unroll
                for (int n = 0; n < 4; ++n)
                    acc[m][n] = __builtin_amdgcn_mfma_f32_16x16x32_bf16(af[m], bfv[n], acc[m][n], 0, 0, 0);
        }
        __syncthreads();
    }

    // epilogue: relu^2 -> bf16, repack via LDS for 16B coalesced stores
    unsigned short* sC = sAB;   // [128][128]
    #pragma unroll
    for (int m = 0; m < 4; ++m)
        #pragma unroll
        for (int n = 0; n < 4; ++n) {
            int col = wc * 64 + n * 16 + (lane & 15);
            #pragma unroll
            for (int i = 0; i < 4; ++i) {
                int row = wr * 64 + m * 16 + (lane >> 4) * 4 + i;
                float v = acc[m][n][i];
                v = v > 0.f ? v * v : 0.f;
                sC[row * 128 + col] = f2bf(v);
            }
        }
    __syncthreads();
    #pragma unroll
    for (int it = 0; it < 8; ++it) {
        int idx = tid + it * 256;
        int row = idx >> 4, j = idx & 15;
        *(int4v*)&H[(size_t)(base + row) * DFF + nt * 128 + j * 8] =
            *(const int4v*)&sC[row * 128 + j * 8];
    }
}

// ---------------- GEMM2: out[tok] += gate * (H @ WpT^T), 64x128 tile, atomic combine ----
__global__ __launch_bounds__(256) void k_gemm2(
    const unsigned short* __restrict__ H, const unsigned short* __restrict__ WpT,
    const int* __restrict__ ctrl, const int* __restrict__ slot_tok,
    const float* __restrict__ slot_gate, float* __restrict__ outp)
{
    int bx = blockIdx.x;                      // grid = MAXT2*NT2 = 480
    int swz = (bx & 7) * (MAXT2 * NT2 / 8) + (bx >> 3);
    int nt = swz / MAXT2, tI = swz % MAXT2;
    if (tI >= ctrl[26]) return;
    int pk = ctrl[128 + tI];
    int e = pk >> 16, mt = pk & 0xffff;
    int base = ctrl[16 + e] + (mt << 6);

    __shared__ unsigned short sA[64 * 64];    // 8 KB
    __shared__ unsigned short sB[128 * 64];   // 16 KB
    __shared__ int sTok[64]; __shared__ float sGate[64];

    int tid = threadIdx.x, w = tid >> 6, lane = tid & 63;
    int wr = w >> 1, wc = w & 1;
    if (tid < 64) {
        sTok[tid] = slot_tok[base + tid];
        sGate[tid] = slot_gate[base + tid];
    }

    const unsigned short* wp = WpT + ((size_t)e * NEMBD + nt * 128) * DFF;
    const unsigned short* aptr[2]; const unsigned short* bptr[4];
    #pragma unroll
    for (int i = 0; i < 2; ++i) {
        int r = i * 32 + w * 8 + (lane >> 3);
        aptr[i] = H + (size_t)(base + r) * DFF + (lane & 7) * 8;
    }
    #pragma unroll
    for (int i = 0; i < 4; ++i) {
        int r = i * 32 + w * 8 + (lane >> 3);
        bptr[i] = wp + (size_t)r * DFF + (lane & 7) * 8;
    }

    f32x4 acc[2][4];
    #pragma unroll
    for (int i = 0; i < 2; ++i)
        #pragma unroll
        for (int j = 0; j < 4; ++j) acc[i][j] = (f32x4){0.f, 0.f, 0.f, 0.f};

    for (int kk = 0; kk < DFF; kk += 64) {
        #pragma unroll
        for (int i = 0; i < 2; ++i)
            gload16(aptr[i] + kk, &sA[(i * 256 + w * 64) * 8]);
        #pragma unroll
        for (int i = 0; i < 4; ++i)
            gload16(bptr[i] + kk, &sB[(i * 256 + w * 64) * 8]);
        __syncthreads();
        #pragma unroll
        for (int kh = 0; kh < 2; ++kh) {
            short8v af[2], bfv[4];
            #pragma unroll
            for (int m = 0; m < 2; ++m)
                af[m] = *(const short8v*)&sA[(wr * 32 + m * 16 + (lane & 15)) * 64 + kh * 32 + (lane >> 4) * 8];
            #pragma unroll
            for (int n = 0; n < 4; ++n)
                bfv[n] = *(const short8v*)&sB[(wc * 64 + n * 16 + (lane & 15)) * 64 + kh * 32 + (lane >> 4) * 8];
            #pragma unroll
            for (int m = 0; m < 2; ++m)
                #pragma unroll
                for (int n = 0; n < 4; ++n)
                    acc[m][n] = __builtin_amdgcn_mfma_f32_16x16x32_bf16(af[m], bfv[n], acc[m][n], 0, 0, 0);
        }
        __syncthreads();
    }

    #pragma unroll
    for (int m = 0; m < 2; ++m)
        #pragma unroll
        for (int n = 0; n < 4; ++n) {
            int col = nt * 128 + wc * 64 + n * 16 + (lane & 15);
            #pragma unroll
            for (int i = 0; i < 4; ++i) {
                int row = wr * 32 + m * 16 + (lane >> 4) * 4 + i;
                atomicAdd(&outp[(size_t)sTok[row] * NEMBD + col], sGate[row] * acc[m][n][i]);
            }
        }
}

// ---------------- aux loss ----------------
__global__ void k_aux(const float* __restrict__ gates, const float* __restrict__ kl_tok,
                      const int* __restrict__ ctrl, float* __restrict__ out_aux)
{
    __shared__ float sred[256];
    int tid = threadIdx.x;
    float p[NEXP]; float kls = 0.f;
    #pragma unroll
    for (int e = 0; e < NEXP; ++e) p[e] = 0.f;
    for (int t = tid; t < NTOK; t += 256) {
        #pragma unroll
        for (int e = 0; e < NEXP; ++e) p[e] += gates[t * NEXP + e];
        kls += kl_tok[t];
    }
    float Ps[NEXP];
    for (int e = 0; e < NEXP; ++e) {
        sred[tid] = p[e]; __syncthreads();
        for (int s = 128; s; s >>= 1) { if (tid < s) sred[tid] += sred[tid + s]; __syncthreads(); }
        if (tid == 0) Ps[e] = sred[0];
        __syncthreads();
    }
    sred[tid] = kls; __syncthreads();
    for (int s = 128; s; s >>= 1) { if (tid < s) sred[tid] += sred[tid + s]; __syncthreads(); }
    if (tid == 0) {
        float kl_mean = sred[0] / (float)NTOK;
        float lb = 0.f;
        for (int e = 0; e < NEXP; ++e)
            lb += ((float)ctrl[e] / (float)(NTOK * 2)) * (Ps[e] / (float)NTOK);
        lb *= (float)NEXP * 0.01f;
        out_aux[0] = lb + kl_mean;
    }
}

extern "C" void kernel_launch(void* const* d_in, const int* in_sizes, int n_in,
                              void* d_out, int out_size, void* d_ws, size_t ws_size,
                              hipStream_t stream) {
    const float* x   = (const float*)d_in[0];
    const float* WgP = (const float*)d_in[1];
    const float* WgQ = (const float*)d_in[2];
    const float* Wfc = (const float*)d_in[3];
    const float* Wpj = (const float*)d_in[4];
    float* out = (float*)d_out;

    char* ws = (char*)d_ws;
    unsigned short* xbf  = (unsigned short*)(ws + WS_XBF);
    float* gates = (float*)(ws + WS_GATES);
    int*   te    = (int*)(ws + WS_TE);
    float* tw    = (float*)(ws + WS_TW);
    float* klt   = (float*)(ws + WS_KL);
    int*   ctrl  = (int*)(ws + WS_CTRL);
    int*   stok  = (int*)(ws + WS_STOK);
    float* sgate = (float*)(ws + WS_SGATE);
    unsigned short* WfcT = (unsigned short*)(ws + WS_WFCT);
    unsigned short* WpT  = (unsigned short*)(ws + WS_WPT);
    unsigned short* H    = (unsigned short*)(ws + WS_H);

    hipMemsetAsync(ctrl, 0, 64, stream);
    hipMemsetAsync(out, 0, (size_t)out_size * 4, stream);
    k_router<<<512, 256, 0, stream>>>(x, WgP, WgQ, xbf, gates, te, tw, klt, ctrl);
    k_transpose<<<NEXP * 12 * 48 + NEXP * 48 * 12, 256, 0, stream>>>(Wfc, WfcT, Wpj, WpT);
    k_sched<<<1, 256, 0, stream>>>(te, tw, ctrl, stok, sgate);
    k_gemm1<<<MAXT1 * NT1, 256, 0, stream>>>(xbf, WfcT, ctrl, stok, H);
    k_gemm2<<<MAXT2 * NT2, 256, 0, stream>>>(H, WpT, ctrl, stok, sgate, out);
    k_aux<<<1, 256, 0, stream>>>(gates, klt, ctrl, out + (size_t)NTOK * NEMBD);
}

// Round 4
// 210.592 us; speedup vs baseline: 1.3702x; 1.3702x over previous
//
#include <hip/hip_runtime.h>
#include <hip/hip_bf16.h>

typedef __attribute__((ext_vector_type(8))) short short8v;   // 8 bf16
typedef __attribute__((ext_vector_type(4))) float f32x4;
typedef __attribute__((ext_vector_type(4))) int int4v;

#define NTOK  2048
#define NEMBD 768
#define DFF   3072
#define NEXP  8
#define MAXSLOT 5120          // 128-aligned per-expert regions, sum <= 5120
#define NT1 24                // DFF/128
#define NT2 6                 // NEMBD/128
#define MAXT1 40              // max 128-row tiles
#define MAXT2 80              // max 64-row tiles

// ---- workspace layout (bytes) ----
#define WS_XBF   0                                   // ushort [2048][768]
#define WS_GATES (WS_XBF + (size_t)NTOK*NEMBD*2)     // float  [2048][8]
#define WS_TE    (WS_GATES + NTOK*8*4)               // int    [2048][2]
#define WS_TW    (WS_TE + NTOK*2*4)                  // float  [2048][2]
#define WS_KL    (WS_TW + NTOK*2*4)                  // float  [2048]
#define WS_CTRL  (WS_KL + NTOK*4)                    // int[512]
#define WS_STOK  (WS_CTRL + 2048)                    // int    [MAXSLOT]
#define WS_TSLOT (WS_STOK + MAXSLOT*4)               // int    [2048][2]
#define WS_WFCT  (WS_TSLOT + NTOK*2*4)               // ushort [8][3072][768]  (obuf aliases this)
#define WS_WPT   (WS_WFCT + (size_t)NEXP*DFF*NEMBD*2)// ushort [8][768][3072]
#define WS_H     (WS_WPT + (size_t)NEXP*NEMBD*DFF*2) // ushort [MAXSLOT][3072]
#define WS_OBUF  WS_WFCT                             // float [MAXSLOT][768] aliases WfcT (dead after gemm1)

__device__ __forceinline__ unsigned short f2bf(float f) {
    union { float f; unsigned u; } v; v.f = f;
    unsigned r = v.u + 0x7fffu + ((v.u >> 16) & 1u);   // RNE
    return (unsigned short)(r >> 16);
}

__device__ __forceinline__ void gload16(const void* g, void* l) {
    __builtin_amdgcn_global_load_lds(
        (const __attribute__((address_space(1))) void*)g,
        (__attribute__((address_space(3))) void*)l, 16, 0, 0);
}

// ---------------- front: weight transpose+convert (blocks 0..1055) + router (1056..1567) ----
__global__ __launch_bounds__(256) void k_front(
    const float* __restrict__ x, const float* __restrict__ WgP, const float* __restrict__ WgQ,
    const float* __restrict__ Wfc, const float* __restrict__ Wpj,
    unsigned short* __restrict__ WfcT, unsigned short* __restrict__ WpT,
    unsigned short* __restrict__ xbf, float* __restrict__ gates,
    int* __restrict__ te, float* __restrict__ tw, float* __restrict__ kl_tok,
    int* __restrict__ ctrl)
{
    __shared__ unsigned short sT[64][72];
    int tid = threadIdx.x;
    int bid = blockIdx.x;
    if (bid < NEXP * 12 * 48 + NEXP * 48 * 12) {
        // -------- transpose+convert: in [E][R][C] f32 -> out [E][C][R] bf16 --------
        const float* in; unsigned short* out; int R, C, tilesC;
        if (bid < NEXP * 12 * 48) { in = Wfc; out = WfcT; R = NEMBD; C = DFF; tilesC = 48; }
        else { bid -= NEXP * 12 * 48; in = Wpj; out = WpT; R = DFF; C = NEMBD; tilesC = 12; }
        int per = (R >> 6) * tilesC;
        int e = bid / per, rem = bid % per;
        int rt = rem / tilesC, ct = rem % tilesC;
        const float* src = in + ((size_t)e * R + rt * 64) * C + ct * 64;
        #pragma unroll
        for (int i = 0; i < 4; ++i) {
            int idx = tid + i * 256;
            int r = idx >> 4, c4 = idx & 15;
            float4 v = *(const float4*)&src[(size_t)r * C + c4 * 4];
            ushort4 o; o.x = f2bf(v.x); o.y = f2bf(v.y); o.z = f2bf(v.z); o.w = f2bf(v.w);
            *(ushort4*)&sT[r][c4 * 4] = o;
        }
        __syncthreads();
        unsigned short* dst = out + ((size_t)e * C + ct * 64) * R + rt * 64;
        #pragma unroll
        for (int i = 0; i < 2; ++i) {
            int idx = tid + i * 256;
            int oc = idx >> 3, j = idx & 7;
            unsigned short u[8];
            #pragma unroll
            for (int s = 0; s < 8; ++s) u[s] = sT[j * 8 + s][oc];
            *(int4v*)&dst[(size_t)oc * R + j * 8] = *(const int4v*)u;
        }
        return;
    }
    // -------- router: one wave per token --------
    int rb = bid - (NEXP * 12 * 48 + NEXP * 48 * 12);   // 0..511
    int wave = tid >> 6, lane = tid & 63;
    int t = rb * 4 + wave;
    int b = t >> 10, l = t & 1023;
    int lf = l + 2; if (lf > 1023) lf = 1023;           // lookforward pad-with-last
    const float* xr = x + (size_t)t * NEMBD;
    const float* xf = x + (size_t)((b << 10) + lf) * NEMBD;
    int e = lane & 7, kg = lane >> 3;

    float accP = 0.f, accQ = 0.f;
    #pragma unroll 8
    for (int i = 0; i < 96; ++i) {
        int k = kg + 8 * i;
        accP += xr[k] * WgP[k * NEXP + e];
        accQ += xf[k] * WgQ[k * NEXP + e];
    }
    #pragma unroll
    for (int off = 8; off < 64; off <<= 1) {
        accP += __shfl_xor(accP, off);
        accQ += __shfl_xor(accQ, off);
    }
    float mq = accQ, mp = accP;
    #pragma unroll
    for (int off = 1; off < 8; off <<= 1) {
        mq = fmaxf(mq, __shfl_xor(mq, off));
        mp = fmaxf(mp, __shfl_xor(mp, off));
    }
    float gq = __expf(accQ - mq), gp = __expf(accP - mp);
    float se = gq, sp = gp;
    #pragma unroll
    for (int off = 1; off < 8; off <<= 1) {
        se += __shfl_xor(se, off);
        sp += __shfl_xor(sp, off);
    }
    float v0 = gq; int e0 = e;
    #pragma unroll
    for (int off = 1; off < 8; off <<= 1) {
        float ov = __shfl_xor(v0, off); int oe = __shfl_xor(e0, off);
        if (ov > v0 || (ov == v0 && oe < e0)) { v0 = ov; e0 = oe; }
    }
    float vx = (e == e0) ? -1.f : gq;
    float v1 = vx; int e1 = e;
    #pragma unroll
    for (int off = 1; off < 8; off <<= 1) {
        float ov = __shfl_xor(v1, off); int oe = __shfl_xor(e1, off);
        if (ov > v1 || (ov == v1 && oe < e1)) { v1 = ov; e1 = oe; }
    }
    float lq = (accQ - mq) - logf(se);
    float lp = (accP - mp) - logf(sp);
    float kl = __expf(lq) * (lq - lp);
    #pragma unroll
    for (int off = 1; off < 8; off <<= 1) kl += __shfl_xor(kl, off);

    if (lane < 8) gates[t * NEXP + e] = gq / se;
    if (lane == 0) {
        float s2 = v0 + v1;
        te[t * 2] = e0; te[t * 2 + 1] = e1;
        tw[t * 2] = v0 / s2; tw[t * 2 + 1] = v1 / s2;
        atomicAdd(&ctrl[e0], 1); atomicAdd(&ctrl[e1], 1);
        kl_tok[t] = kl;
    }
    // x -> bf16 for this router block's 4 token rows
    const float4* xs4 = (const float4*)(x + (size_t)rb * 4 * NEMBD);
    ushort4* xd4 = (ushort4*)(xbf + (size_t)rb * 4 * NEMBD);
    for (int i = tid; i < 4 * NEMBD / 4; i += 256) {
        float4 v = xs4[i];
        ushort4 o;
        o.x = f2bf(v.x); o.y = f2bf(v.y); o.z = f2bf(v.z); o.w = f2bf(v.w);
        xd4[i] = o;
    }
}

// ---------------- sched: offsets + tile tables + slot lists (1 block) ----------------
// ctrl: [0..7] counts, [16..23] expert base, [24] total, [25] nt1, [26] nt2,
//       [64..103] t1 (e<<16|mt), [128..207] t2
__global__ __launch_bounds__(256) void k_sched(
    const int* __restrict__ te, int* __restrict__ ctrl,
    int* __restrict__ stok, int* __restrict__ tslot)
{
    __shared__ int cur[NEXP];
    int tid = threadIdx.x;
    if (tid == 0) {
        int off = 0, n1 = 0, n2 = 0;
        for (int e = 0; e < NEXP; ++e) {
            ctrl[16 + e] = off;
            int t128 = (ctrl[e] + 127) >> 7;
            for (int m = 0; m < t128; ++m)     ctrl[64 + n1++]  = (e << 16) | m;
            for (int m = 0; m < 2 * t128; ++m) ctrl[128 + n2++] = (e << 16) | m;
            off += t128 << 7;
        }
        ctrl[24] = off; ctrl[25] = n1; ctrl[26] = n2;
    }
    if (tid < NEXP) cur[tid] = 0;
    for (int i = tid; i < MAXSLOT; i += 256) stok[i] = 0;
    __syncthreads();
    for (int t = tid; t < NTOK; t += 256) {
        #pragma unroll
        for (int k = 0; k < 2; ++k) {
            int e = te[t * 2 + k];
            int s = atomicAdd(&cur[e], 1);
            int flat = ctrl[16 + e] + s;
            stok[flat] = t; tslot[t * 2 + k] = flat;
        }
    }
}

// ---------------- GEMM1: H = relu(Xg @ WfcT^T)^2, 128x128 tile, BK=64, XOR-swizzled LDS ----
__global__ __launch_bounds__(256) void k_gemm1(
    const unsigned short* __restrict__ xbf, const unsigned short* __restrict__ WfcT,
    const int* __restrict__ ctrl, const int* __restrict__ slot_tok,
    unsigned short* __restrict__ H)
{
    int bx = blockIdx.x;                      // grid = MAXT1*NT1 = 960
    int swz = (bx & 7) * (MAXT1 * NT1 / 8) + (bx >> 3);
    int nt = swz / MAXT1, tI = swz % MAXT1;
    if (tI >= ctrl[25]) return;
    int pk = ctrl[64 + tI];
    int e = pk >> 16, mt = pk & 0xffff;
    int base = ctrl[16 + e] + (mt << 7);

    __shared__ unsigned short sAB[2 * 128 * 64];   // sA | sB, reused as sC[128][128]
    unsigned short* sA = sAB;
    unsigned short* sB = sAB + 128 * 64;

    int tid = threadIdx.x, w = tid >> 6, lane = tid & 63;
    int wr = w >> 1, wc = w & 1;

    // source pre-swizzle: physical slot (lane&7) must hold global slot (lane&7)^(row&7),
    // row&7 = (lane>>3)&7 for the staging pattern
    int swsub = (((lane & 7) ^ ((lane >> 3) & 7)) << 3);
    const unsigned short* wfc = WfcT + ((size_t)e * DFF + nt * 128) * NEMBD;
    const unsigned short* aptr[4]; const unsigned short* bptr[4];
    #pragma unroll
    for (int i = 0; i < 4; ++i) {
        int r = i * 32 + w * 8 + (lane >> 3);
        aptr[i] = xbf + (size_t)slot_tok[base + r] * NEMBD + swsub;
        bptr[i] = wfc + (size_t)r * NEMBD + swsub;
    }

    f32x4 acc[4][4];
    #pragma unroll
    for (int i = 0; i < 4; ++i)
        #pragma unroll
        for (int j = 0; j < 4; ++j) acc[i][j] = (f32x4){0.f, 0.f, 0.f, 0.f};

    int rsw = (lane & 7) << 3;   // read-side XOR: (row&7)<<3, row&7 == lane&7
    for (int kk = 0; kk < NEMBD; kk += 64) {
        #pragma unroll
        for (int i = 0; i < 4; ++i) {
            gload16(aptr[i] + kk, &sA[(i * 256 + w * 64) * 8]);
            gload16(bptr[i] + kk, &sB[(i * 256 + w * 64) * 8]);
        }
        __syncthreads();
        #pragma unroll
        for (int kh = 0; kh < 2; ++kh) {
            int c = (kh * 32 + ((lane >> 4) << 3)) ^ rsw;
            short8v af[4], bfv[4];
            #pragma unroll
            for (int m = 0; m < 4; ++m)
                af[m] = *(const short8v*)&sA[(wr * 64 + m * 16 + (lane & 15)) * 64 + c];
            #pragma unroll
            for (int n = 0; n < 4; ++n)
                bfv[n] = *(const short8v*)&sB[(wc * 64 + n * 16 + (lane & 15)) * 64 + c];
            #pragma unroll
            for (int m = 0; m < 4; ++m)
                #pragma unroll
                for (int n = 0; n < 4; ++n)
                    acc[m][n] = __builtin_amdgcn_mfma_f32_16x16x32_bf16(af[m], bfv[n], acc[m][n], 0, 0, 0);
        }
        __syncthreads();
    }

    // epilogue: relu^2 -> bf16, repack via LDS for 16B coalesced stores
    unsigned short* sC = sAB;   // [128][128]
    #pragma unroll
    for (int m = 0; m < 4; ++m)
        #pragma unroll
        for (int n = 0; n < 4; ++n) {
            int col = wc * 64 + n * 16 + (lane & 15);
            #pragma unroll
            for (int i = 0; i < 4; ++i) {
                int row = wr * 64 + m * 16 + (lane >> 4) * 4 + i;
                float v = acc[m][n][i];
                v = v > 0.f ? v * v : 0.f;
                sC[row * 128 + col] = f2bf(v);
            }
        }
    __syncthreads();
    #pragma unroll
    for (int it = 0; it < 8; ++it) {
        int idx = tid + it * 256;
        int row = idx >> 4, j = idx & 15;
        *(int4v*)&H[(size_t)(base + row) * DFF + nt * 128 + j * 8] =
            *(const int4v*)&sC[row * 128 + j * 8];
    }
}

// ---------------- GEMM2: obuf[slot] = H @ WpT^T, 64x128 tile, BK=64, XOR-swizzled LDS ----
__global__ __launch_bounds__(256) void k_gemm2(
    const unsigned short* __restrict__ H, const unsigned short* __restrict__ WpT,
    const int* __restrict__ ctrl, float* __restrict__ obuf)
{
    int bx = blockIdx.x;                      // grid = MAXT2*NT2 = 480
    int swz = (bx & 7) * (MAXT2 * NT2 / 8) + (bx >> 3);
    int nt = swz / MAXT2, tI = swz % MAXT2;
    if (tI >= ctrl[26]) return;
    int pk = ctrl[128 + tI];
    int e = pk >> 16, mt = pk & 0xffff;
    int base = ctrl[16 + e] + (mt << 6);

    __shared__ unsigned short sA[64 * 64];    // 8 KB
    __shared__ unsigned short sB[128 * 64];   // 16 KB

    int tid = threadIdx.x, w = tid >> 6, lane = tid & 63;
    int wr = w >> 1, wc = w & 1;

    int swsub = (((lane & 7) ^ ((lane >> 3) & 7)) << 3);
    const unsigned short* wp = WpT + ((size_t)e * NEMBD + nt * 128) * DFF;
    const unsigned short* aptr[2]; const unsigned short* bptr[4];
    #pragma unroll
    for (int i = 0; i < 2; ++i) {
        int r = i * 32 + w * 8 + (lane >> 3);
        aptr[i] = H + (size_t)(base + r) * DFF + swsub;
    }
    #pragma unroll
    for (int i = 0; i < 4; ++i) {
        int r = i * 32 + w * 8 + (lane >> 3);
        bptr[i] = wp + (size_t)r * DFF + swsub;
    }

    f32x4 acc[2][4];
    #pragma unroll
    for (int i = 0; i < 2; ++i)
        #pragma unroll
        for (int j = 0; j < 4; ++j) acc[i][j] = (f32x4){0.f, 0.f, 0.f, 0.f};

    int rsw = (lane & 7) << 3;
    for (int kk = 0; kk < DFF; kk += 64) {
        #pragma unroll
        for (int i = 0; i < 2; ++i)
            gload16(aptr[i] + kk, &sA[(i * 256 + w * 64) * 8]);
        #pragma unroll
        for (int i = 0; i < 4; ++i)
            gload16(bptr[i] + kk, &sB[(i * 256 + w * 64) * 8]);
        __syncthreads();
        #pragma unroll
        for (int kh = 0; kh < 2; ++kh) {
            int c = (kh * 32 + ((lane >> 4) << 3)) ^ rsw;
            short8v af[2], bfv[4];
            #pragma unroll
            for (int m = 0; m < 2; ++m)
                af[m] = *(const short8v*)&sA[(wr * 32 + m * 16 + (lane & 15)) * 64 + c];
            #pragma unroll
            for (int n = 0; n < 4; ++n)
                bfv[n] = *(const short8v*)&sB[(wc * 64 + n * 16 + (lane & 15)) * 64 + c];
            #pragma unroll
            for (int m = 0; m < 2; ++m)
                #pragma unroll
                for (int n = 0; n < 4; ++n)
                    acc[m][n] = __builtin_amdgcn_mfma_f32_16x16x32_bf16(af[m], bfv[n], acc[m][n], 0, 0, 0);
        }
        __syncthreads();
    }

    #pragma unroll
    for (int m = 0; m < 2; ++m)
        #pragma unroll
        for (int n = 0; n < 4; ++n) {
            int col = nt * 128 + wc * 64 + n * 16 + (lane & 15);
            #pragma unroll
            for (int i = 0; i < 4; ++i) {
                int row = wr * 32 + m * 16 + (lane >> 4) * 4 + i;
                obuf[(size_t)(base + row) * NEMBD + col] = acc[m][n][i];
            }
        }
}

// ---------------- finish: combine (blocks 0..511) + aux loss (block 512) ----------------
__global__ __launch_bounds__(256) void k_finish(
    const float* __restrict__ obuf, const int* __restrict__ tslot,
    const float* __restrict__ tw, const float* __restrict__ gates,
    const float* __restrict__ kl_tok, const int* __restrict__ ctrl,
    float* __restrict__ out)
{
    int tid = threadIdx.x;
    if (blockIdx.x == 512) {
        __shared__ float sred[256];
        float p[NEXP]; float kls = 0.f;
        #pragma unroll
        for (int e = 0; e < NEXP; ++e) p[e] = 0.f;
        for (int t = tid; t < NTOK; t += 256) {
            #pragma unroll
            for (int e = 0; e < NEXP; ++e) p[e] += gates[t * NEXP + e];
            kls += kl_tok[t];
        }
        float Ps[NEXP];
        for (int e = 0; e < NEXP; ++e) {
            sred[tid] = p[e]; __syncthreads();
            for (int s = 128; s; s >>= 1) { if (tid < s) sred[tid] += sred[tid + s]; __syncthreads(); }
            if (tid == 0) Ps[e] = sred[0];
            __syncthreads();
        }
        sred[tid] = kls; __syncthreads();
        for (int s = 128; s; s >>= 1) { if (tid < s) sred[tid] += sred[tid + s]; __syncthreads(); }
        if (tid == 0) {
            float kl_mean = sred[0] / (float)NTOK;
            float lb = 0.f;
            for (int e = 0; e < NEXP; ++e)
                lb += ((float)ctrl[e] / (float)(NTOK * 2)) * (Ps[e] / (float)NTOK);
            lb *= (float)NEXP * 0.01f;
            out[(size_t)NTOK * NEMBD] = lb + kl_mean;
        }
        return;
    }
    int wave = tid >> 6, lane = tid & 63;
    int t = blockIdx.x * 4 + wave;
    int s0 = tslot[t * 2], s1 = tslot[t * 2 + 1];
    float g0 = tw[t * 2], g1 = tw[t * 2 + 1];
    const float4* r0 = (const float4*)(obuf + (size_t)s0 * NEMBD);
    const float4* r1 = (const float4*)(obuf + (size_t)s1 * NEMBD);
    float4* o4 = (float4*)(out + (size_t)t * NEMBD);
    #pragma unroll
    for (int j = 0; j < 3; ++j) {
        int c = j * 64 + lane;
        float4 a = r0[c], b = r1[c];
        float4 o;
        o.x = g0 * a.x + g1 * b.x; o.y = g0 * a.y + g1 * b.y;
        o.z = g0 * a.z + g1 * b.z; o.w = g0 * a.w + g1 * b.w;
        o4[c] = o;
    }
}

extern "C" void kernel_launch(void* const* d_in, const int* in_sizes, int n_in,
                              void* d_out, int out_size, void* d_ws, size_t ws_size,
                              hipStream_t stream) {
    const float* x   = (const float*)d_in[0];
    const float* WgP = (const float*)d_in[1];
    const float* WgQ = (const float*)d_in[2];
    const float* Wfc = (const float*)d_in[3];
    const float* Wpj = (const float*)d_in[4];
    float* out = (float*)d_out;

    char* ws = (char*)d_ws;
    unsigned short* xbf  = (unsigned short*)(ws + WS_XBF);
    float* gates = (float*)(ws + WS_GATES);
    int*   te    = (int*)(ws + WS_TE);
    float* tw    = (float*)(ws + WS_TW);
    float* klt   = (float*)(ws + WS_KL);
    int*   ctrl  = (int*)(ws + WS_CTRL);
    int*   stok  = (int*)(ws + WS_STOK);
    int*   tslot = (int*)(ws + WS_TSLOT);
    unsigned short* WfcT = (unsigned short*)(ws + WS_WFCT);
    unsigned short* WpT  = (unsigned short*)(ws + WS_WPT);
    unsigned short* H    = (unsigned short*)(ws + WS_H);
    float* obuf  = (float*)(ws + WS_OBUF);   // aliases WfcT (dead after gemm1)

    hipMemsetAsync(ctrl, 0, 64, stream);
    k_front<<<NEXP * 12 * 48 + NEXP * 48 * 12 + 512, 256, 0, stream>>>(
        x, WgP, WgQ, Wfc, Wpj, WfcT, WpT, xbf, gates, te, tw, klt, ctrl);
    k_sched<<<1, 256, 0, stream>>>(te, ctrl, stok, tslot);
    k_gemm1<<<MAXT1 * NT1, 256, 0, stream>>>(xbf, WfcT, ctrl, stok, H);
    k_gemm2<<<MAXT2 * NT2, 256, 0, stream>>>(H, WpT, ctrl, obuf);
    k_finish<<<513, 256, 0, stream>>>(obuf, tslot, tw, gates, klt, ctrl, out);
}

// Round 5
// 174.771 us; speedup vs baseline: 1.6510x; 1.2050x over previous
//
#include <hip/hip_runtime.h>
#include <hip/hip_bf16.h>

typedef __attribute__((ext_vector_type(8))) short short8v;   // 8 bf16
typedef __attribute__((ext_vector_type(4))) float f32x4;
typedef __attribute__((ext_vector_type(4))) int int4v;

#define NTOK  2048
#define NEMBD 768
#define DFF   3072
#define NEXP  8
#define MAXSLOT 5120          // 128-aligned per-expert regions, sum <= 5120
#define NT1 24                // DFF/128
#define NT2 6                 // NEMBD/128
#define MAXT1 40              // max 128-row tiles
#define MAXT2 80              // max 64-row tiles

// ---- workspace layout (bytes) ----
#define WS_XBF   0                                   // ushort [2048][768]
#define WS_GATES (WS_XBF + (size_t)NTOK*NEMBD*2)     // float  [2048][8]
#define WS_TE    (WS_GATES + NTOK*8*4)               // int    [2048][2]
#define WS_TW    (WS_TE + NTOK*2*4)                  // float  [2048][2]
#define WS_KL    (WS_TW + NTOK*2*4)                  // float  [2048]
#define WS_CTRL  (WS_KL + NTOK*4)                    // int[512]
#define WS_STOK  (WS_CTRL + 2048)                    // int    [MAXSLOT]
#define WS_TSLOT (WS_STOK + MAXSLOT*4)               // int    [2048][2]
#define WS_WFCT  (WS_TSLOT + NTOK*2*4)               // ushort [8][3072][768]  (obuf aliases this)
#define WS_WPT   (WS_WFCT + (size_t)NEXP*DFF*NEMBD*2)// ushort [8][768][3072]
#define WS_H     (WS_WPT + (size_t)NEXP*NEMBD*DFF*2) // ushort [MAXSLOT][3072]
#define WS_OBUF  WS_WFCT                             // float [MAXSLOT][768] aliases WfcT (dead after gemm1)

__device__ __forceinline__ unsigned short f2bf(float f) {
    union { float f; unsigned u; } v; v.f = f;
    unsigned r = v.u + 0x7fffu + ((v.u >> 16) & 1u);   // RNE
    return (unsigned short)(r >> 16);
}

__device__ __forceinline__ void gload16(const void* g, void* l) {
    __builtin_amdgcn_global_load_lds(
        (const __attribute__((address_space(1))) void*)g,
        (__attribute__((address_space(3))) void*)l, 16, 0, 0);
}

// ---------------- front: weight transpose+convert (blocks 0..9215) + router (9216..9727) ----
__global__ __launch_bounds__(256) void k_front(
    const float* __restrict__ x, const float* __restrict__ WgP, const float* __restrict__ WgQ,
    const float* __restrict__ Wfc, const float* __restrict__ Wpj,
    unsigned short* __restrict__ WfcT, unsigned short* __restrict__ WpT,
    unsigned short* __restrict__ xbf, float* __restrict__ gates,
    int* __restrict__ te, float* __restrict__ tw, float* __restrict__ kl_tok)
{
    __shared__ unsigned short sT[64][72];
    int tid = threadIdx.x;
    int bid = blockIdx.x;
    if (bid < NEXP * 12 * 48 + NEXP * 48 * 12) {
        // -------- transpose+convert: in [E][R][C] f32 -> out [E][C][R] bf16 --------
        const float* in; unsigned short* out; int R, C, tilesC;
        if (bid < NEXP * 12 * 48) { in = Wfc; out = WfcT; R = NEMBD; C = DFF; tilesC = 48; }
        else { bid -= NEXP * 12 * 48; in = Wpj; out = WpT; R = DFF; C = NEMBD; tilesC = 12; }
        int per = (R >> 6) * tilesC;
        int e = bid / per, rem = bid % per;
        int rt = rem / tilesC, ct = rem % tilesC;
        const float* src = in + ((size_t)e * R + rt * 64) * C + ct * 64;
        #pragma unroll
        for (int i = 0; i < 4; ++i) {
            int idx = tid + i * 256;
            int r = idx >> 4, c4 = idx & 15;
            float4 v = *(const float4*)&src[(size_t)r * C + c4 * 4];
            ushort4 o; o.x = f2bf(v.x); o.y = f2bf(v.y); o.z = f2bf(v.z); o.w = f2bf(v.w);
            *(ushort4*)&sT[r][c4 * 4] = o;
        }
        __syncthreads();
        unsigned short* dst = out + ((size_t)e * C + ct * 64) * R + rt * 64;
        #pragma unroll
        for (int i = 0; i < 2; ++i) {
            int idx = tid + i * 256;
            int oc = idx >> 3, j = idx & 7;
            unsigned short u[8];
            #pragma unroll
            for (int s = 0; s < 8; ++s) u[s] = sT[j * 8 + s][oc];
            *(int4v*)&dst[(size_t)oc * R + j * 8] = *(const int4v*)u;
        }
        return;
    }
    // -------- router: one wave per token, NO global atomics --------
    int rb = bid - (NEXP * 12 * 48 + NEXP * 48 * 12);   // 0..511
    int wave = tid >> 6, lane = tid & 63;
    int t = rb * 4 + wave;
    int b = t >> 10, l = t & 1023;
    int lf = l + 2; if (lf > 1023) lf = 1023;           // lookforward pad-with-last
    const float* xr = x + (size_t)t * NEMBD;
    const float* xf = x + (size_t)((b << 10) + lf) * NEMBD;
    int e = lane & 7, kg = lane >> 3;

    float accP = 0.f, accQ = 0.f;
    #pragma unroll 8
    for (int i = 0; i < 96; ++i) {
        int k = kg + 8 * i;
        accP += xr[k] * WgP[k * NEXP + e];
        accQ += xf[k] * WgQ[k * NEXP + e];
    }
    #pragma unroll
    for (int off = 8; off < 64; off <<= 1) {
        accP += __shfl_xor(accP, off);
        accQ += __shfl_xor(accQ, off);
    }
    float mq = accQ, mp = accP;
    #pragma unroll
    for (int off = 1; off < 8; off <<= 1) {
        mq = fmaxf(mq, __shfl_xor(mq, off));
        mp = fmaxf(mp, __shfl_xor(mp, off));
    }
    float gq = __expf(accQ - mq), gp = __expf(accP - mp);
    float se = gq, sp = gp;
    #pragma unroll
    for (int off = 1; off < 8; off <<= 1) {
        se += __shfl_xor(se, off);
        sp += __shfl_xor(sp, off);
    }
    float v0 = gq; int e0 = e;
    #pragma unroll
    for (int off = 1; off < 8; off <<= 1) {
        float ov = __shfl_xor(v0, off); int oe = __shfl_xor(e0, off);
        if (ov > v0 || (ov == v0 && oe < e0)) { v0 = ov; e0 = oe; }
    }
    float vx = (e == e0) ? -1.f : gq;
    float v1 = vx; int e1 = e;
    #pragma unroll
    for (int off = 1; off < 8; off <<= 1) {
        float ov = __shfl_xor(v1, off); int oe = __shfl_xor(e1, off);
        if (ov > v1 || (ov == v1 && oe < e1)) { v1 = ov; e1 = oe; }
    }
    float lq = (accQ - mq) - logf(se);
    float lp = (accP - mp) - logf(sp);
    float kl = __expf(lq) * (lq - lp);
    #pragma unroll
    for (int off = 1; off < 8; off <<= 1) kl += __shfl_xor(kl, off);

    if (lane < 8) gates[t * NEXP + e] = gq / se;
    if (lane == 0) {
        float s2 = v0 + v1;
        te[t * 2] = e0; te[t * 2 + 1] = e1;
        tw[t * 2] = v0 / s2; tw[t * 2 + 1] = v1 / s2;
        kl_tok[t] = kl;
    }
    // x -> bf16 for this router block's 4 token rows
    const float4* xs4 = (const float4*)(x + (size_t)rb * 4 * NEMBD);
    ushort4* xd4 = (ushort4*)(xbf + (size_t)rb * 4 * NEMBD);
    for (int i = tid; i < 4 * NEMBD / 4; i += 256) {
        float4 v = xs4[i];
        ushort4 o;
        o.x = f2bf(v.x); o.y = f2bf(v.y); o.z = f2bf(v.z); o.w = f2bf(v.w);
        xd4[i] = o;
    }
}

// ---------------- sched: histogram + offsets + tile tables + slot lists (1 block) ---------
// ctrl: [0..7] counts, [16..23] expert base, [24] total, [25] nt1, [26] nt2,
//       [64..103] t1 (e<<16|mt), [128..207] t2
__global__ __launch_bounds__(256) void k_sched(
    const int* __restrict__ te, int* __restrict__ ctrl,
    int* __restrict__ stok, int* __restrict__ tslot)
{
    __shared__ int cur[NEXP];
    __shared__ int cnt_s[NEXP];
    __shared__ int sOff[NEXP];
    int tid = threadIdx.x, lane = tid & 63;
    if (tid < NEXP) { cur[tid] = 0; cnt_s[tid] = 0; }
    for (int i = tid; i < MAXSLOT; i += 256) stok[i] = 0;
    __syncthreads();
    // histogram over te[0..4095], static-indexed per-thread counters
    int cc[NEXP];
    #pragma unroll
    for (int e = 0; e < NEXP; ++e) cc[e] = 0;
    for (int i = tid; i < NTOK * 2; i += 256) {
        int e = te[i];
        #pragma unroll
        for (int q = 0; q < NEXP; ++q) cc[q] += (e == q) ? 1 : 0;
    }
    #pragma unroll
    for (int e = 0; e < NEXP; ++e) {
        int v = cc[e];
        #pragma unroll
        for (int off = 32; off; off >>= 1) v += __shfl_xor(v, off);
        if (lane == 0) atomicAdd(&cnt_s[e], v);
    }
    __syncthreads();
    if (tid == 0) {
        int off = 0, n1 = 0, n2 = 0;
        for (int e = 0; e < NEXP; ++e) {
            int cnt = cnt_s[e];
            ctrl[e] = cnt;
            ctrl[16 + e] = off; sOff[e] = off;
            int t128 = (cnt + 127) >> 7;
            for (int m = 0; m < t128; ++m)     ctrl[64 + n1++]  = (e << 16) | m;
            for (int m = 0; m < 2 * t128; ++m) ctrl[128 + n2++] = (e << 16) | m;
            off += t128 << 7;
        }
        ctrl[24] = off; ctrl[25] = n1; ctrl[26] = n2;
    }
    __syncthreads();
    for (int t = tid; t < NTOK; t += 256) {
        #pragma unroll
        for (int k = 0; k < 2; ++k) {
            int e = te[t * 2 + k];
            int s = atomicAdd(&cur[e], 1);
            int flat = sOff[e] + s;
            stok[flat] = t; tslot[t * 2 + k] = flat;
        }
    }
}

// ---------------- GEMM1: H = relu(Xg @ WfcT^T)^2, 128x128 tile, BK=64, XOR-swizzled LDS ----
__global__ __launch_bounds__(256) void k_gemm1(
    const unsigned short* __restrict__ xbf, const unsigned short* __restrict__ WfcT,
    const int* __restrict__ ctrl, const int* __restrict__ slot_tok,
    unsigned short* __restrict__ H)
{
    int bx = blockIdx.x;                      // grid = MAXT1*NT1 = 960
    int swz = (bx & 7) * (MAXT1 * NT1 / 8) + (bx >> 3);
    int nt = swz / MAXT1, tI = swz % MAXT1;
    if (tI >= ctrl[25]) return;
    int pk = ctrl[64 + tI];
    int e = pk >> 16, mt = pk & 0xffff;
    int base = ctrl[16 + e] + (mt << 7);

    __shared__ unsigned short sAB[2 * 128 * 64];   // sA | sB, reused as sC[128][128]
    unsigned short* sA = sAB;
    unsigned short* sB = sAB + 128 * 64;

    int tid = threadIdx.x, w = tid >> 6, lane = tid & 63;
    int wr = w >> 1, wc = w & 1;

    // source pre-swizzle: physical slot (lane&7) must hold global slot (lane&7)^(row&7),
    // row&7 = (lane>>3)&7 for the staging pattern
    int swsub = (((lane & 7) ^ ((lane >> 3) & 7)) << 3);
    const unsigned short* wfc = WfcT + ((size_t)e * DFF + nt * 128) * NEMBD;
    const unsigned short* aptr[4]; const unsigned short* bptr[4];
    #pragma unroll
    for (int i = 0; i < 4; ++i) {
        int r = i * 32 + w * 8 + (lane >> 3);
        aptr[i] = xbf + (size_t)slot_tok[base + r] * NEMBD + swsub;
        bptr[i] = wfc + (size_t)r * NEMBD + swsub;
    }

    f32x4 acc[4][4];
    #pragma unroll
    for (int i = 0; i < 4; ++i)
        #pragma unroll
        for (int j = 0; j < 4; ++j) acc[i][j] = (f32x4){0.f, 0.f, 0.f, 0.f};

    int rsw = (lane & 7) << 3;   // read-side XOR: (row&7)<<3, row&7 == lane&7
    for (int kk = 0; kk < NEMBD; kk += 64) {
        #pragma unroll
        for (int i = 0; i < 4; ++i) {
            gload16(aptr[i] + kk, &sA[(i * 256 + w * 64) * 8]);
            gload16(bptr[i] + kk, &sB[(i * 256 + w * 64) * 8]);
        }
        __syncthreads();
        #pragma unroll
        for (int kh = 0; kh < 2; ++kh) {
            int c = (kh * 32 + ((lane >> 4) << 3)) ^ rsw;
            short8v af[4], bfv[4];
            #pragma unroll
            for (int m = 0; m < 4; ++m)
                af[m] = *(const short8v*)&sA[(wr * 64 + m * 16 + (lane & 15)) * 64 + c];
            #pragma unroll
            for (int n = 0; n < 4; ++n)
                bfv[n] = *(const short8v*)&sB[(wc * 64 + n * 16 + (lane & 15)) * 64 + c];
            #pragma unroll
            for (int m = 0; m < 4; ++m)
                #pragma unroll
                for (int n = 0; n < 4; ++n)
                    acc[m][n] = __builtin_amdgcn_mfma_f32_16x16x32_bf16(af[m], bfv[n], acc[m][n], 0, 0, 0);
        }
        __syncthreads();
    }

    // epilogue: relu^2 -> bf16, repack via LDS for 16B coalesced stores
    unsigned short* sC = sAB;   // [128][128]
    #pragma unroll
    for (int m = 0; m < 4; ++m)
        #pragma unroll
        for (int n = 0; n < 4; ++n) {
            int col = wc * 64 + n * 16 + (lane & 15);
            #pragma unroll
            for (int i = 0; i < 4; ++i) {
                int row = wr * 64 + m * 16 + (lane >> 4) * 4 + i;
                float v = acc[m][n][i];
                v = v > 0.f ? v * v : 0.f;
                sC[row * 128 + col] = f2bf(v);
            }
        }
    __syncthreads();
    #pragma unroll
    for (int it = 0; it < 8; ++it) {
        int idx = tid + it * 256;
        int row = idx >> 4, j = idx & 15;
        *(int4v*)&H[(size_t)(base + row) * DFF + nt * 128 + j * 8] =
            *(const int4v*)&sC[row * 128 + j * 8];
    }
}

// ---------------- GEMM2: obuf[slot] = H @ WpT^T, 64x128 tile, BK=64, XOR-swizzled LDS ----
__global__ __launch_bounds__(256) void k_gemm2(
    const unsigned short* __restrict__ H, const unsigned short* __restrict__ WpT,
    const int* __restrict__ ctrl, float* __restrict__ obuf)
{
    int bx = blockIdx.x;                      // grid = MAXT2*NT2 = 480
    int swz = (bx & 7) * (MAXT2 * NT2 / 8) + (bx >> 3);
    int nt = swz / MAXT2, tI = swz % MAXT2;
    if (tI >= ctrl[26]) return;
    int pk = ctrl[128 + tI];
    int e = pk >> 16, mt = pk & 0xffff;
    int base = ctrl[16 + e] + (mt << 6);

    __shared__ unsigned short sA[64 * 64];    // 8 KB
    __shared__ unsigned short sB[128 * 64];   // 16 KB

    int tid = threadIdx.x, w = tid >> 6, lane = tid & 63;
    int wr = w >> 1, wc = w & 1;

    int swsub = (((lane & 7) ^ ((lane >> 3) & 7)) << 3);
    const unsigned short* wp = WpT + ((size_t)e * NEMBD + nt * 128) * DFF;
    const unsigned short* aptr[2]; const unsigned short* bptr[4];
    #pragma unroll
    for (int i = 0; i < 2; ++i) {
        int r = i * 32 + w * 8 + (lane >> 3);
        aptr[i] = H + (size_t)(base + r) * DFF + swsub;
    }
    #pragma unroll
    for (int i = 0; i < 4; ++i) {
        int r = i * 32 + w * 8 + (lane >> 3);
        bptr[i] = wp + (size_t)r * DFF + swsub;
    }

    f32x4 acc[2][4];
    #pragma unroll
    for (int i = 0; i < 2; ++i)
        #pragma unroll
        for (int j = 0; j < 4; ++j) acc[i][j] = (f32x4){0.f, 0.f, 0.f, 0.f};

    int rsw = (lane & 7) << 3;
    for (int kk = 0; kk < DFF; kk += 64) {
        #pragma unroll
        for (int i = 0; i < 2; ++i)
            gload16(aptr[i] + kk, &sA[(i * 256 + w * 64) * 8]);
        #pragma unroll
        for (int i = 0; i < 4; ++i)
            gload16(bptr[i] + kk, &sB[(i * 256 + w * 64) * 8]);
        __syncthreads();
        #pragma unroll
        for (int kh = 0; kh < 2; ++kh) {
            int c = (kh * 32 + ((lane >> 4) << 3)) ^ rsw;
            short8v af[2], bfv[4];
            #pragma unroll
            for (int m = 0; m < 2; ++m)
                af[m] = *(const short8v*)&sA[(wr * 32 + m * 16 + (lane & 15)) * 64 + c];
            #pragma unroll
            for (int n = 0; n < 4; ++n)
                bfv[n] = *(const short8v*)&sB[(wc * 64 + n * 16 + (lane & 15)) * 64 + c];
            #pragma unroll
            for (int m = 0; m < 2; ++m)
                #pragma unroll
                for (int n = 0; n < 4; ++n)
                    acc[m][n] = __builtin_amdgcn_mfma_f32_16x16x32_bf16(af[m], bfv[n], acc[m][n], 0, 0, 0);
        }
        __syncthreads();
    }

    #pragma unroll
    for (int m = 0; m < 2; ++m)
        #pragma unroll
        for (int n = 0; n < 4; ++n) {
            int col = nt * 128 + wc * 64 + n * 16 + (lane & 15);
            #pragma unroll
            for (int i = 0; i < 4; ++i) {
                int row = wr * 32 + m * 16 + (lane >> 4) * 4 + i;
                obuf[(size_t)(base + row) * NEMBD + col] = acc[m][n][i];
            }
        }
}

// ---------------- finish: combine (blocks 0..511) + aux loss (block 512) ----------------
__global__ __launch_bounds__(256) void k_finish(
    const float* __restrict__ obuf, const int* __restrict__ tslot,
    const float* __restrict__ tw, const float* __restrict__ gates,
    const float* __restrict__ kl_tok, const int* __restrict__ ctrl,
    float* __restrict__ out)
{
    int tid = threadIdx.x;
    if (blockIdx.x == 512) {
        __shared__ float sred[256];
        float p[NEXP]; float kls = 0.f;
        #pragma unroll
        for (int e = 0; e < NEXP; ++e) p[e] = 0.f;
        for (int t = tid; t < NTOK; t += 256) {
            #pragma unroll
            for (int e = 0; e < NEXP; ++e) p[e] += gates[t * NEXP + e];
            kls += kl_tok[t];
        }
        float Ps[NEXP];
        for (int e = 0; e < NEXP; ++e) {
            sred[tid] = p[e]; __syncthreads();
            for (int s = 128; s; s >>= 1) { if (tid < s) sred[tid] += sred[tid + s]; __syncthreads(); }
            if (tid == 0) Ps[e] = sred[0];
            __syncthreads();
        }
        sred[tid] = kls; __syncthreads();
        for (int s = 128; s; s >>= 1) { if (tid < s) sred[tid] += sred[tid + s]; __syncthreads(); }
        if (tid == 0) {
            float kl_mean = sred[0] / (float)NTOK;
            float lb = 0.f;
            for (int e = 0; e < NEXP; ++e)
                lb += ((float)ctrl[e] / (float)(NTOK * 2)) * (Ps[e] / (float)NTOK);
            lb *= (float)NEXP * 0.01f;
            out[(size_t)NTOK * NEMBD] = lb + kl_mean;
        }
        return;
    }
    int wave = tid >> 6, lane = tid & 63;
    int t = blockIdx.x * 4 + wave;
    int s0 = tslot[t * 2], s1 = tslot[t * 2 + 1];
    float g0 = tw[t * 2], g1 = tw[t * 2 + 1];
    const float4* r0 = (const float4*)(obuf + (size_t)s0 * NEMBD);
    const float4* r1 = (const float4*)(obuf + (size_t)s1 * NEMBD);
    float4* o4 = (float4*)(out + (size_t)t * NEMBD);
    #pragma unroll
    for (int j = 0; j < 3; ++j) {
        int c = j * 64 + lane;
        float4 a = r0[c], b = r1[c];
        float4 o;
        o.x = g0 * a.x + g1 * b.x; o.y = g0 * a.y + g1 * b.y;
        o.z = g0 * a.z + g1 * b.z; o.w = g0 * a.w + g1 * b.w;
        o4[c] = o;
    }
}

extern "C" void kernel_launch(void* const* d_in, const int* in_sizes, int n_in,
                              void* d_out, int out_size, void* d_ws, size_t ws_size,
                              hipStream_t stream) {
    const float* x   = (const float*)d_in[0];
    const float* WgP = (const float*)d_in[1];
    const float* WgQ = (const float*)d_in[2];
    const float* Wfc = (const float*)d_in[3];
    const float* Wpj = (const float*)d_in[4];
    float* out = (float*)d_out;

    char* ws = (char*)d_ws;
    unsigned short* xbf  = (unsigned short*)(ws + WS_XBF);
    float* gates = (float*)(ws + WS_GATES);
    int*   te    = (int*)(ws + WS_TE);
    float* tw    = (float*)(ws + WS_TW);
    float* klt   = (float*)(ws + WS_KL);
    int*   ctrl  = (int*)(ws + WS_CTRL);
    int*   stok  = (int*)(ws + WS_STOK);
    int*   tslot = (int*)(ws + WS_TSLOT);
    unsigned short* WfcT = (unsigned short*)(ws + WS_WFCT);
    unsigned short* WpT  = (unsigned short*)(ws + WS_WPT);
    unsigned short* H    = (unsigned short*)(ws + WS_H);
    float* obuf  = (float*)(ws + WS_OBUF);   // aliases WfcT (dead after gemm1)

    hipMemsetAsync(ctrl, 0, 64, stream);
    k_front<<<NEXP * 12 * 48 + NEXP * 48 * 12 + 512, 256, 0, stream>>>(
        x, WgP, WgQ, Wfc, Wpj, WfcT, WpT, xbf, gates, te, tw, klt);
    k_sched<<<1, 256, 0, stream>>>(te, ctrl, stok, tslot);
    k_gemm1<<<MAXT1 * NT1, 256, 0, stream>>>(xbf, WfcT, ctrl, stok, H);
    k_gemm2<<<MAXT2 * NT2, 256, 0, stream>>>(H, WpT, ctrl, obuf);
    k_finish<<<513, 256, 0, stream>>>(obuf, tslot, tw, gates, klt, ctrl, out);
}

// Round 6
// 167.210 us; speedup vs baseline: 1.7257x; 1.0452x over previous
//
#include <hip/hip_runtime.h>
#include <hip/hip_bf16.h>

typedef __attribute__((ext_vector_type(8))) short short8v;   // 8 bf16
typedef __attribute__((ext_vector_type(4))) float f32x4;
typedef __attribute__((ext_vector_type(4))) int int4v;

#define NTOK  2048
#define NEMBD 768
#define DFF   3072
#define NEXP  8
#define MAXSLOT 5120          // 128-aligned per-expert regions, sum <= 5120
#define NT1 24                // DFF/128
#define NT2 6                 // NEMBD/128
#define MAXT1 40              // max 128-row tiles
#define MAXT2 80              // max 64-row tiles
#define NTRB  4608            // transpose blocks (2304 Wfc + 2304 Wp)

// ---- workspace layout (bytes) ----
#define WS_XBF   0                                   // ushort [2048][768]
#define WS_GATES (WS_XBF + (size_t)NTOK*NEMBD*2)     // float  [2048][8]
#define WS_TE    (WS_GATES + NTOK*8*4)               // int    [2048][2]
#define WS_TW    (WS_TE + NTOK*2*4)                  // float  [2048][2]
#define WS_KL    (WS_TW + NTOK*2*4)                  // float  [2048]
#define WS_CTRL  (WS_KL + NTOK*4)                    // int[512]
#define WS_STOK  (WS_CTRL + 2048)                    // int    [MAXSLOT]
#define WS_TSLOT (WS_STOK + MAXSLOT*4)               // int    [2048][2]
#define WS_WFCT  (WS_TSLOT + NTOK*2*4)               // ushort [8][3072][768]  (obuf aliases this)
#define WS_WPT   (WS_WFCT + (size_t)NEXP*DFF*NEMBD*2)// ushort [8][768][3072]
#define WS_H     (WS_WPT + (size_t)NEXP*NEMBD*DFF*2) // ushort [MAXSLOT][3072]
#define WS_OBUF  WS_WFCT                             // float [MAXSLOT][768] aliases WfcT (dead after gemm1)

__device__ __forceinline__ unsigned short f2bf(float f) {
    union { float f; unsigned u; } v; v.f = f;
    unsigned r = v.u + 0x7fffu + ((v.u >> 16) & 1u);   // RNE
    return (unsigned short)(r >> 16);
}

__device__ __forceinline__ void gload16(const void* g, void* l) {
    __builtin_amdgcn_global_load_lds(
        (const __attribute__((address_space(1))) void*)g,
        (__attribute__((address_space(3))) void*)l, 16, 0, 0);
}

// ---------------- front: weight transpose+convert (blocks 0..4607) + router (4608..5119) ----
// Transpose: in [E][R][C] f32 -> out [E][C][R] bf16, tile 64 rows x 128 cols.
// Phase 1: 8x4 micro-transpose in registers -> ds_write_b128 into [c][kslot] LDS.
// Phase 2: ds_read_b128 rows -> 128B-coalesced global stores. Slot XOR (c>>3)&7 both ways.
__global__ __launch_bounds__(256) void k_front(
    const float* __restrict__ x, const float* __restrict__ WgP, const float* __restrict__ WgQ,
    const float* __restrict__ Wfc, const float* __restrict__ Wpj,
    unsigned short* __restrict__ WfcT, unsigned short* __restrict__ WpT,
    unsigned short* __restrict__ xbf, float* __restrict__ gates,
    int* __restrict__ te, float* __restrict__ tw, float* __restrict__ kl_tok)
{
    __shared__ unsigned short sT[128 * 64];   // [c=128][8 slots of 8 bf16] = 16 KB
    int tid = threadIdx.x;
    int bid = blockIdx.x;
    if (bid < NTRB) {
        const float* in; unsigned short* out; int R, C, tilesC;
        if (bid < NTRB / 2) { in = Wfc; out = WfcT; R = NEMBD; C = DFF; tilesC = 24; }
        else { bid -= NTRB / 2; in = Wpj; out = WpT; R = DFF; C = NEMBD; tilesC = 6; }
        int e = bid / 288, rem = bid % 288;
        int rt = rem / tilesC, ct = rem % tilesC;
        int cg = tid & 31, rg = tid >> 5;
        // phase 1: load 8 rows x 4 cols, convert, register-transpose, vector LDS write
        const float* src = in + ((size_t)e * R + rt * 64 + rg * 8) * C + ct * 128 + cg * 4;
        unsigned short cb[4][8];
        #pragma unroll
        for (int i = 0; i < 8; ++i) {
            float4 v = *(const float4*)&src[(size_t)i * C];
            cb[0][i] = f2bf(v.x); cb[1][i] = f2bf(v.y);
            cb[2][i] = f2bf(v.z); cb[3][i] = f2bf(v.w);
        }
        #pragma unroll
        for (int j = 0; j < 4; ++j) {
            int c = cg * 4 + j;
            int sl = rg ^ ((c >> 3) & 7);
            *(int4v*)&sT[c * 64 + sl * 8] = *(const int4v*)&cb[j][0];
        }
        __syncthreads();
        // phase 2: vector LDS reads, 128B-coalesced stores
        unsigned short* dstp = out + ((size_t)e * C + ct * 128) * R + rt * 64;
        #pragma unroll
        for (int i = 0; i < 4; ++i) {
            int idx = tid + i * 256;
            int c = idx >> 3, s = idx & 7;
            int sl = s ^ ((c >> 3) & 7);
            *(int4v*)&dstp[(size_t)c * R + s * 8] = *(const int4v*)&sT[c * 64 + sl * 8];
        }
        return;
    }
    // -------- router: one wave per token, no global atomics --------
    int rb = bid - NTRB;   // 0..511
    int wave = tid >> 6, lane = tid & 63;
    int t = rb * 4 + wave;
    int b = t >> 10, l = t & 1023;
    int lf = l + 2; if (lf > 1023) lf = 1023;           // lookforward pad-with-last
    const float* xr = x + (size_t)t * NEMBD;
    const float* xf = x + (size_t)((b << 10) + lf) * NEMBD;
    int e = lane & 7, kg = lane >> 3;

    float accP = 0.f, accQ = 0.f;
    #pragma unroll 8
    for (int i = 0; i < 96; ++i) {
        int k = kg + 8 * i;
        accP += xr[k] * WgP[k * NEXP + e];
        accQ += xf[k] * WgQ[k * NEXP + e];
    }
    #pragma unroll
    for (int off = 8; off < 64; off <<= 1) {
        accP += __shfl_xor(accP, off);
        accQ += __shfl_xor(accQ, off);
    }
    float mq = accQ, mp = accP;
    #pragma unroll
    for (int off = 1; off < 8; off <<= 1) {
        mq = fmaxf(mq, __shfl_xor(mq, off));
        mp = fmaxf(mp, __shfl_xor(mp, off));
    }
    float gq = __expf(accQ - mq), gp = __expf(accP - mp);
    float se = gq, sp = gp;
    #pragma unroll
    for (int off = 1; off < 8; off <<= 1) {
        se += __shfl_xor(se, off);
        sp += __shfl_xor(sp, off);
    }
    float v0 = gq; int e0 = e;
    #pragma unroll
    for (int off = 1; off < 8; off <<= 1) {
        float ov = __shfl_xor(v0, off); int oe = __shfl_xor(e0, off);
        if (ov > v0 || (ov == v0 && oe < e0)) { v0 = ov; e0 = oe; }
    }
    float vx = (e == e0) ? -1.f : gq;
    float v1 = vx; int e1 = e;
    #pragma unroll
    for (int off = 1; off < 8; off <<= 1) {
        float ov = __shfl_xor(v1, off); int oe = __shfl_xor(e1, off);
        if (ov > v1 || (ov == v1 && oe < e1)) { v1 = ov; e1 = oe; }
    }
    float lq = (accQ - mq) - logf(se);
    float lp = (accP - mp) - logf(sp);
    float kl = __expf(lq) * (lq - lp);
    #pragma unroll
    for (int off = 1; off < 8; off <<= 1) kl += __shfl_xor(kl, off);

    if (lane < 8) gates[t * NEXP + e] = gq / se;
    if (lane == 0) {
        float s2 = v0 + v1;
        te[t * 2] = e0; te[t * 2 + 1] = e1;
        tw[t * 2] = v0 / s2; tw[t * 2 + 1] = v1 / s2;
        kl_tok[t] = kl;
    }
    // x -> bf16 for this router block's 4 token rows
    const float4* xs4 = (const float4*)(x + (size_t)rb * 4 * NEMBD);
    ushort4* xd4 = (ushort4*)(xbf + (size_t)rb * 4 * NEMBD);
    for (int i = tid; i < 4 * NEMBD / 4; i += 256) {
        float4 v = xs4[i];
        ushort4 o;
        o.x = f2bf(v.x); o.y = f2bf(v.y); o.z = f2bf(v.z); o.w = f2bf(v.w);
        xd4[i] = o;
    }
}

// ---------------- sched: histogram + offsets + tile tables + slot lists (1 block) ---------
// ctrl: [0..7] counts, [16..23] expert base, [24] total, [25] nt1, [26] nt2,
//       [64..103] t1 (e<<16|mt), [128..207] t2
__global__ __launch_bounds__(256) void k_sched(
    const int* __restrict__ te, int* __restrict__ ctrl,
    int* __restrict__ stok, int* __restrict__ tslot)
{
    __shared__ int cur[NEXP];
    __shared__ int cnt_s[NEXP];
    __shared__ int sOff[NEXP];
    int tid = threadIdx.x, lane = tid & 63;
    if (tid < NEXP) { cur[tid] = 0; cnt_s[tid] = 0; }
    for (int i = tid; i < MAXSLOT; i += 256) stok[i] = 0;
    __syncthreads();
    // histogram over te[0..4095], static-indexed per-thread counters
    int cc[NEXP];
    #pragma unroll
    for (int e = 0; e < NEXP; ++e) cc[e] = 0;
    for (int i = tid; i < NTOK * 2; i += 256) {
        int e = te[i];
        #pragma unroll
        for (int q = 0; q < NEXP; ++q) cc[q] += (e == q) ? 1 : 0;
    }
    #pragma unroll
    for (int e = 0; e < NEXP; ++e) {
        int v = cc[e];
        #pragma unroll
        for (int off = 32; off; off >>= 1) v += __shfl_xor(v, off);
        if (lane == 0) atomicAdd(&cnt_s[e], v);
    }
    __syncthreads();
    if (tid == 0) {
        int off = 0, n1 = 0, n2 = 0;
        for (int e = 0; e < NEXP; ++e) {
            int cnt = cnt_s[e];
            ctrl[e] = cnt;
            ctrl[16 + e] = off; sOff[e] = off;
            int t128 = (cnt + 127) >> 7;
            for (int m = 0; m < t128; ++m)     ctrl[64 + n1++]  = (e << 16) | m;
            for (int m = 0; m < 2 * t128; ++m) ctrl[128 + n2++] = (e << 16) | m;
            off += t128 << 7;
        }
        ctrl[24] = off; ctrl[25] = n1; ctrl[26] = n2;
    }
    __syncthreads();
    for (int t = tid; t < NTOK; t += 256) {
        #pragma unroll
        for (int k = 0; k < 2; ++k) {
            int e = te[t * 2 + k];
            int s = atomicAdd(&cur[e], 1);
            int flat = sOff[e] + s;
            stok[flat] = t; tslot[t * 2 + k] = flat;
        }
    }
}

// ---------------- GEMM1: H = relu(Xg @ WfcT^T)^2, 128x128 tile, BK=64, XOR-swizzled LDS ----
__global__ __launch_bounds__(256) void k_gemm1(
    const unsigned short* __restrict__ xbf, const unsigned short* __restrict__ WfcT,
    const int* __restrict__ ctrl, const int* __restrict__ slot_tok,
    unsigned short* __restrict__ H)
{
    int bx = blockIdx.x;                      // grid = MAXT1*NT1 = 960
    int swz = (bx & 7) * (MAXT1 * NT1 / 8) + (bx >> 3);
    int nt = swz / MAXT1, tI = swz % MAXT1;
    if (tI >= ctrl[25]) return;
    int pk = ctrl[64 + tI];
    int e = pk >> 16, mt = pk & 0xffff;
    int base = ctrl[16 + e] + (mt << 7);

    __shared__ unsigned short sAB[2 * 128 * 64];   // sA | sB, reused as sC[128][128]
    unsigned short* sA = sAB;
    unsigned short* sB = sAB + 128 * 64;

    int tid = threadIdx.x, w = tid >> 6, lane = tid & 63;
    int wr = w >> 1, wc = w & 1;

    // source pre-swizzle: physical slot (lane&7) must hold global slot (lane&7)^(row&7),
    // row&7 = (lane>>3)&7 for the staging pattern
    int swsub = (((lane & 7) ^ ((lane >> 3) & 7)) << 3);
    const unsigned short* wfc = WfcT + ((size_t)e * DFF + nt * 128) * NEMBD;
    const unsigned short* aptr[4]; const unsigned short* bptr[4];
    #pragma unroll
    for (int i = 0; i < 4; ++i) {
        int r = i * 32 + w * 8 + (lane >> 3);
        aptr[i] = xbf + (size_t)slot_tok[base + r] * NEMBD + swsub;
        bptr[i] = wfc + (size_t)r * NEMBD + swsub;
    }

    f32x4 acc[4][4];
    #pragma unroll
    for (int i = 0; i < 4; ++i)
        #pragma unroll
        for (int j = 0; j < 4; ++j) acc[i][j] = (f32x4){0.f, 0.f, 0.f, 0.f};

    int rsw = (lane & 7) << 3;   // read-side XOR: (row&7)<<3, row&7 == lane&7
    for (int kk = 0; kk < NEMBD; kk += 64) {
        #pragma unroll
        for (int i = 0; i < 4; ++i) {
            gload16(aptr[i] + kk, &sA[(i * 256 + w * 64) * 8]);
            gload16(bptr[i] + kk, &sB[(i * 256 + w * 64) * 8]);
        }
        __syncthreads();
        #pragma unroll
        for (int kh = 0; kh < 2; ++kh) {
            int c = (kh * 32 + ((lane >> 4) << 3)) ^ rsw;
            short8v af[4], bfv[4];
            #pragma unroll
            for (int m = 0; m < 4; ++m)
                af[m] = *(const short8v*)&sA[(wr * 64 + m * 16 + (lane & 15)) * 64 + c];
            #pragma unroll
            for (int n = 0; n < 4; ++n)
                bfv[n] = *(const short8v*)&sB[(wc * 64 + n * 16 + (lane & 15)) * 64 + c];
            #pragma unroll
            for (int m = 0; m < 4; ++m)
                #pragma unroll
                for (int n = 0; n < 4; ++n)
                    acc[m][n] = __builtin_amdgcn_mfma_f32_16x16x32_bf16(af[m], bfv[n], acc[m][n], 0, 0, 0);
        }
        __syncthreads();
    }

    // epilogue: relu^2 -> bf16, repack via LDS for 16B coalesced stores
    unsigned short* sC = sAB;   // [128][128]
    #pragma unroll
    for (int m = 0; m < 4; ++m)
        #pragma unroll
        for (int n = 0; n < 4; ++n) {
            int col = wc * 64 + n * 16 + (lane & 15);
            #pragma unroll
            for (int i = 0; i < 4; ++i) {
                int row = wr * 64 + m * 16 + (lane >> 4) * 4 + i;
                float v = acc[m][n][i];
                v = v > 0.f ? v * v : 0.f;
                sC[row * 128 + col] = f2bf(v);
            }
        }
    __syncthreads();
    #pragma unroll
    for (int it = 0; it < 8; ++it) {
        int idx = tid + it * 256;
        int row = idx >> 4, j = idx & 15;
        *(int4v*)&H[(size_t)(base + row) * DFF + nt * 128 + j * 8] =
            *(const int4v*)&sC[row * 128 + j * 8];
    }
}

// ---------------- GEMM2: obuf[slot] = H @ WpT^T, 64x128 tile, BK=64, XOR-swizzled LDS ----
__global__ __launch_bounds__(256) void k_gemm2(
    const unsigned short* __restrict__ H, const unsigned short* __restrict__ WpT,
    const int* __restrict__ ctrl, float* __restrict__ obuf)
{
    int bx = blockIdx.x;                      // grid = MAXT2*NT2 = 480
    int swz = (bx & 7) * (MAXT2 * NT2 / 8) + (bx >> 3);
    int nt = swz / MAXT2, tI = swz % MAXT2;
    if (tI >= ctrl[26]) return;
    int pk = ctrl[128 + tI];
    int e = pk >> 16, mt = pk & 0xffff;
    int base = ctrl[16 + e] + (mt << 6);

    __shared__ unsigned short sA[64 * 64];    // 8 KB
    __shared__ unsigned short sB[128 * 64];   // 16 KB

    int tid = threadIdx.x, w = tid >> 6, lane = tid & 63;
    int wr = w >> 1, wc = w & 1;

    int swsub = (((lane & 7) ^ ((lane >> 3) & 7)) << 3);
    const unsigned short* wp = WpT + ((size_t)e * NEMBD + nt * 128) * DFF;
    const unsigned short* aptr[2]; const unsigned short* bptr[4];
    #pragma unroll
    for (int i = 0; i < 2; ++i) {
        int r = i * 32 + w * 8 + (lane >> 3);
        aptr[i] = H + (size_t)(base + r) * DFF + swsub;
    }
    #pragma unroll
    for (int i = 0; i < 4; ++i) {
        int r = i * 32 + w * 8 + (lane >> 3);
        bptr[i] = wp + (size_t)r * DFF + swsub;
    }

    f32x4 acc[2][4];
    #pragma unroll
    for (int i = 0; i < 2; ++i)
        #pragma unroll
        for (int j = 0; j < 4; ++j) acc[i][j] = (f32x4){0.f, 0.f, 0.f, 0.f};

    int rsw = (lane & 7) << 3;
    for (int kk = 0; kk < DFF; kk += 64) {
        #pragma unroll
        for (int i = 0; i < 2; ++i)
            gload16(aptr[i] + kk, &sA[(i * 256 + w * 64) * 8]);
        #pragma unroll
        for (int i = 0; i < 4; ++i)
            gload16(bptr[i] + kk, &sB[(i * 256 + w * 64) * 8]);
        __syncthreads();
        #pragma unroll
        for (int kh = 0; kh < 2; ++kh) {
            int c = (kh * 32 + ((lane >> 4) << 3)) ^ rsw;
            short8v af[2], bfv[4];
            #pragma unroll
            for (int m = 0; m < 2; ++m)
                af[m] = *(const short8v*)&sA[(wr * 32 + m * 16 + (lane & 15)) * 64 + c];
            #pragma unroll
            for (int n = 0; n < 4; ++n)
                bfv[n] = *(const short8v*)&sB[(wc * 64 + n * 16 + (lane & 15)) * 64 + c];
            #pragma unroll
            for (int m = 0; m < 2; ++m)
                #pragma unroll
                for (int n = 0; n < 4; ++n)
                    acc[m][n] = __builtin_amdgcn_mfma_f32_16x16x32_bf16(af[m], bfv[n], acc[m][n], 0, 0, 0);
        }
        __syncthreads();
    }

    #pragma unroll
    for (int m = 0; m < 2; ++m)
        #pragma unroll
        for (int n = 0; n < 4; ++n) {
            int col = nt * 128 + wc * 64 + n * 16 + (lane & 15);
            #pragma unroll
            for (int i = 0; i < 4; ++i) {
                int row = wr * 32 + m * 16 + (lane >> 4) * 4 + i;
                obuf[(size_t)(base + row) * NEMBD + col] = acc[m][n][i];
            }
        }
}

// ---------------- finish: combine (blocks 0..511) + aux loss (block 512) ----------------
__global__ __launch_bounds__(256) void k_finish(
    const float* __restrict__ obuf, const int* __restrict__ tslot,
    const float* __restrict__ tw, const float* __restrict__ gates,
    const float* __restrict__ kl_tok, const int* __restrict__ ctrl,
    float* __restrict__ out)
{
    int tid = threadIdx.x;
    if (blockIdx.x == 512) {
        __shared__ float sred[256];
        float p[NEXP]; float kls = 0.f;
        #pragma unroll
        for (int e = 0; e < NEXP; ++e) p[e] = 0.f;
        for (int t = tid; t < NTOK; t += 256) {
            #pragma unroll
            for (int e = 0; e < NEXP; ++e) p[e] += gates[t * NEXP + e];
            kls += kl_tok[t];
        }
        float Ps[NEXP];
        for (int e = 0; e < NEXP; ++e) {
            sred[tid] = p[e]; __syncthreads();
            for (int s = 128; s; s >>= 1) { if (tid < s) sred[tid] += sred[tid + s]; __syncthreads(); }
            if (tid == 0) Ps[e] = sred[0];
            __syncthreads();
        }
        sred[tid] = kls; __syncthreads();
        for (int s = 128; s; s >>= 1) { if (tid < s) sred[tid] += sred[tid + s]; __syncthreads(); }
        if (tid == 0) {
            float kl_mean = sred[0] / (float)NTOK;
            float lb = 0.f;
            for (int e = 0; e < NEXP; ++e)
                lb += ((float)ctrl[e] / (float)(NTOK * 2)) * (Ps[e] / (float)NTOK);
            lb *= (float)NEXP * 0.01f;
            out[(size_t)NTOK * NEMBD] = lb + kl_mean;
        }
        return;
    }
    int wave = tid >> 6, lane = tid & 63;
    int t = blockIdx.x * 4 + wave;
    int s0 = tslot[t * 2], s1 = tslot[t * 2 + 1];
    float g0 = tw[t * 2], g1 = tw[t * 2 + 1];
    const float4* r0 = (const float4*)(obuf + (size_t)s0 * NEMBD);
    const float4* r1 = (const float4*)(obuf + (size_t)s1 * NEMBD);
    float4* o4 = (float4*)(out + (size_t)t * NEMBD);
    #pragma unroll
    for (int j = 0; j < 3; ++j) {
        int c = j * 64 + lane;
        float4 a = r0[c], b = r1[c];
        float4 o;
        o.x = g0 * a.x + g1 * b.x; o.y = g0 * a.y + g1 * b.y;
        o.z = g0 * a.z + g1 * b.z; o.w = g0 * a.w + g1 * b.w;
        o4[c] = o;
    }
}

extern "C" void kernel_launch(void* const* d_in, const int* in_sizes, int n_in,
                              void* d_out, int out_size, void* d_ws, size_t ws_size,
                              hipStream_t stream) {
    const float* x   = (const float*)d_in[0];
    const float* WgP = (const float*)d_in[1];
    const float* WgQ = (const float*)d_in[2];
    const float* Wfc = (const float*)d_in[3];
    const float* Wpj = (const float*)d_in[4];
    float* out = (float*)d_out;

    char* ws = (char*)d_ws;
    unsigned short* xbf  = (unsigned short*)(ws + WS_XBF);
    float* gates = (float*)(ws + WS_GATES);
    int*   te    = (int*)(ws + WS_TE);
    float* tw    = (float*)(ws + WS_TW);
    float* klt   = (float*)(ws + WS_KL);
    int*   ctrl  = (int*)(ws + WS_CTRL);
    int*   stok  = (int*)(ws + WS_STOK);
    int*   tslot = (int*)(ws + WS_TSLOT);
    unsigned short* WfcT = (unsigned short*)(ws + WS_WFCT);
    unsigned short* WpT  = (unsigned short*)(ws + WS_WPT);
    unsigned short* H    = (unsigned short*)(ws + WS_H);
    float* obuf  = (float*)(ws + WS_OBUF);   // aliases WfcT (dead after gemm1)

    k_front<<<NTRB + 512, 256, 0, stream>>>(
        x, WgP, WgQ, Wfc, Wpj, WfcT, WpT, xbf, gates, te, tw, klt);
    k_sched<<<1, 256, 0, stream>>>(te, ctrl, stok, tslot);
    k_gemm1<<<MAXT1 * NT1, 256, 0, stream>>>(xbf, WfcT, ctrl, stok, H);
    k_gemm2<<<MAXT2 * NT2, 256, 0, stream>>>(H, WpT, ctrl, obuf);
    k_finish<<<513, 256, 0, stream>>>(obuf, tslot, tw, gates, klt, ctrl, out);
}

// Round 7
// 160.143 us; speedup vs baseline: 1.8018x; 1.0441x over previous
//
#include <hip/hip_runtime.h>
#include <hip/hip_bf16.h>

typedef __attribute__((ext_vector_type(8))) short short8v;   // 8 bf16
typedef __attribute__((ext_vector_type(4))) float f32x4;
typedef __attribute__((ext_vector_type(4))) int int4v;

#define NTOK  2048
#define NEMBD 768
#define DFF   3072
#define NEXP  8
#define MAXSLOT 5120          // 128-aligned per-expert regions, sum <= 5120
#define NT1 24                // DFF/128
#define NT2 6                 // NEMBD/128
#define MAXT1 40              // max 128-row tiles
#define MAXT2 80              // max 64-row tiles
#define NTRB  2304            // transpose blocks (1152 Wfc + 1152 Wp), 256k x 64n tiles

// ---- workspace layout (bytes) ----
#define WS_XBF   0                                   // ushort [2048][768]
#define WS_GATES (WS_XBF + (size_t)NTOK*NEMBD*2)     // float  [2048][8]
#define WS_TE    (WS_GATES + NTOK*8*4)               // int    [2048][2]
#define WS_TW    (WS_TE + NTOK*2*4)                  // float  [2048][2]
#define WS_KL    (WS_TW + NTOK*2*4)                  // float  [2048]
#define WS_CTRL  (WS_KL + NTOK*4)                    // int[512]
#define WS_STOK  (WS_CTRL + 2048)                    // int    [MAXSLOT]
#define WS_TSLOT (WS_STOK + MAXSLOT*4)               // int    [2048][2]
#define WS_WFCT  (WS_TSLOT + NTOK*2*4)               // ushort [8][3072][768]  (obuf aliases this)
#define WS_WPT   (WS_WFCT + (size_t)NEXP*DFF*NEMBD*2)// ushort [8][768][3072]
#define WS_H     (WS_WPT + (size_t)NEXP*NEMBD*DFF*2) // ushort [MAXSLOT][3072]
#define WS_OBUF  WS_WFCT                             // float [MAXSLOT][768] aliases WfcT (dead after gemm1)

__device__ __forceinline__ unsigned short f2bf(float f) {
    union { float f; unsigned u; } v; v.f = f;
    unsigned r = v.u + 0x7fffu + ((v.u >> 16) & 1u);   // RNE
    return (unsigned short)(r >> 16);
}

__device__ __forceinline__ void gload16(const void* g, void* l) {
    __builtin_amdgcn_global_load_lds(
        (const __attribute__((address_space(1))) void*)g,
        (__attribute__((address_space(3))) void*)l, 16, 0, 0);
}

// ---------------- front: weight transpose+convert (blocks 0..2303) + router (2304..2815) ----
// Transpose tile: 256 k-rows x 64 n-cols. Reads: 256B segments per k-row (full lines).
// Writes: 512B contiguous per output n-row (full lines, no write-allocate RMW).
// LDS: [n=64][slot=32] x 16B, slot XOR (n&7); b128 both phases.
__global__ __launch_bounds__(256) void k_front(
    const float* __restrict__ x, const float* __restrict__ WgP, const float* __restrict__ WgQ,
    const float* __restrict__ Wfc, const float* __restrict__ Wpj,
    unsigned short* __restrict__ WfcT, unsigned short* __restrict__ WpT,
    unsigned short* __restrict__ xbf, float* __restrict__ gates,
    int* __restrict__ te, float* __restrict__ tw, float* __restrict__ kl_tok)
{
    __shared__ unsigned short sT[64 * 32 * 8];   // 32 KB
    int tid = threadIdx.x;
    int bid = blockIdx.x;
    if (bid < NTRB) {
        const float* in; unsigned short* out; int R, C, tilesC;
        if (bid < NTRB / 2) { in = Wfc; out = WfcT; R = NEMBD; C = DFF; tilesC = 48; }
        else { bid -= NTRB / 2; in = Wpj; out = WpT; R = DFF; C = NEMBD; tilesC = 12; }
        int e = bid / 144, rem = bid % 144;
        int rt = rem / tilesC, ct = rem % tilesC;
        // phase 1: thread reads 8 k-rows x 8 n-cols (2 float4/row), register-transpose,
        // 8 x ds_write_b128 into [n][kg^j] slots
        int ng = tid & 7, kg = tid >> 3;        // ng: n-group (8 cols), kg: k-group (8 rows)
        const float* src = in + ((size_t)e * R + rt * 256 + kg * 8) * C + ct * 64 + ng * 8;
        unsigned short cb[8][8];
        #pragma unroll
        for (int i = 0; i < 8; ++i) {
            float4 a = *(const float4*)&src[(size_t)i * C];
            float4 b = *(const float4*)&src[(size_t)i * C + 4];
            cb[0][i] = f2bf(a.x); cb[1][i] = f2bf(a.y); cb[2][i] = f2bf(a.z); cb[3][i] = f2bf(a.w);
            cb[4][i] = f2bf(b.x); cb[5][i] = f2bf(b.y); cb[6][i] = f2bf(b.z); cb[7][i] = f2bf(b.w);
        }
        #pragma unroll
        for (int j = 0; j < 8; ++j) {
            int n = ng * 8 + j;
            int sl = kg ^ j;                    // n&7 == j; bijective
            *(int4v*)&sT[((size_t)n * 32 + sl) * 8] = *(const int4v*)&cb[j][0];
        }
        __syncthreads();
        // phase 2: thread writes 128B contiguous (8 x b128) of one output n-row
        unsigned short* dstp = out + ((size_t)e * C + ct * 64) * R + rt * 256;
        int n2 = tid >> 2, cs = tid & 3;
        #pragma unroll
        for (int i = 0; i < 8; ++i) {
            int s = cs * 8 + i;
            int sl = s ^ (n2 & 7);
            *(int4v*)&dstp[(size_t)n2 * R + s * 8] = *(const int4v*)&sT[((size_t)n2 * 32 + sl) * 8];
        }
        return;
    }
    // -------- router: one wave per token, no global atomics --------
    int rb = bid - NTRB;   // 0..511
    int wave = tid >> 6, lane = tid & 63;
    int t = rb * 4 + wave;
    int b = t >> 10, l = t & 1023;
    int lf = l + 2; if (lf > 1023) lf = 1023;           // lookforward pad-with-last
    const float* xr = x + (size_t)t * NEMBD;
    const float* xf = x + (size_t)((b << 10) + lf) * NEMBD;
    int e = lane & 7, kg = lane >> 3;

    float accP = 0.f, accQ = 0.f;
    #pragma unroll 8
    for (int i = 0; i < 96; ++i) {
        int k = kg + 8 * i;
        accP += xr[k] * WgP[k * NEXP + e];
        accQ += xf[k] * WgQ[k * NEXP + e];
    }
    #pragma unroll
    for (int off = 8; off < 64; off <<= 1) {
        accP += __shfl_xor(accP, off);
        accQ += __shfl_xor(accQ, off);
    }
    float mq = accQ, mp = accP;
    #pragma unroll
    for (int off = 1; off < 8; off <<= 1) {
        mq = fmaxf(mq, __shfl_xor(mq, off));
        mp = fmaxf(mp, __shfl_xor(mp, off));
    }
    float gq = __expf(accQ - mq), gp = __expf(accP - mp);
    float se = gq, sp = gp;
    #pragma unroll
    for (int off = 1; off < 8; off <<= 1) {
        se += __shfl_xor(se, off);
        sp += __shfl_xor(sp, off);
    }
    float v0 = gq; int e0 = e;
    #pragma unroll
    for (int off = 1; off < 8; off <<= 1) {
        float ov = __shfl_xor(v0, off); int oe = __shfl_xor(e0, off);
        if (ov > v0 || (ov == v0 && oe < e0)) { v0 = ov; e0 = oe; }
    }
    float vx = (e == e0) ? -1.f : gq;
    float v1 = vx; int e1 = e;
    #pragma unroll
    for (int off = 1; off < 8; off <<= 1) {
        float ov = __shfl_xor(v1, off); int oe = __shfl_xor(e1, off);
        if (ov > v1 || (ov == v1 && oe < e1)) { v1 = ov; e1 = oe; }
    }
    float lq = (accQ - mq) - logf(se);
    float lp = (accP - mp) - logf(sp);
    float kl = __expf(lq) * (lq - lp);
    #pragma unroll
    for (int off = 1; off < 8; off <<= 1) kl += __shfl_xor(kl, off);

    if (lane < 8) gates[t * NEXP + e] = gq / se;
    if (lane == 0) {
        float s2 = v0 + v1;
        te[t * 2] = e0; te[t * 2 + 1] = e1;
        tw[t * 2] = v0 / s2; tw[t * 2 + 1] = v1 / s2;
        kl_tok[t] = kl;
    }
    // x -> bf16 for this router block's 4 token rows
    const float4* xs4 = (const float4*)(x + (size_t)rb * 4 * NEMBD);
    ushort4* xd4 = (ushort4*)(xbf + (size_t)rb * 4 * NEMBD);
    for (int i = tid; i < 4 * NEMBD / 4; i += 256) {
        float4 v = xs4[i];
        ushort4 o;
        o.x = f2bf(v.x); o.y = f2bf(v.y); o.z = f2bf(v.z); o.w = f2bf(v.w);
        xd4[i] = o;
    }
}

// ---------------- sched: histogram + offsets + tile tables + slot lists (1 block) ---------
// ctrl: [0..7] counts, [16..23] expert base, [24] total, [25] nt1, [26] nt2,
//       [64..103] t1 (e<<16|mt), [128..207] t2
__global__ __launch_bounds__(256) void k_sched(
    const int* __restrict__ te, int* __restrict__ ctrl,
    int* __restrict__ stok, int* __restrict__ tslot)
{
    __shared__ int cur[NEXP];
    __shared__ int cnt_s[NEXP];
    __shared__ int sOff[NEXP];
    int tid = threadIdx.x, lane = tid & 63;
    if (tid < NEXP) { cur[tid] = 0; cnt_s[tid] = 0; }
    for (int i = tid; i < MAXSLOT; i += 256) stok[i] = 0;
    __syncthreads();
    // histogram over te[0..4095], static-indexed per-thread counters
    int cc[NEXP];
    #pragma unroll
    for (int e = 0; e < NEXP; ++e) cc[e] = 0;
    for (int i = tid; i < NTOK * 2; i += 256) {
        int e = te[i];
        #pragma unroll
        for (int q = 0; q < NEXP; ++q) cc[q] += (e == q) ? 1 : 0;
    }
    #pragma unroll
    for (int e = 0; e < NEXP; ++e) {
        int v = cc[e];
        #pragma unroll
        for (int off = 32; off; off >>= 1) v += __shfl_xor(v, off);
        if (lane == 0) atomicAdd(&cnt_s[e], v);
    }
    __syncthreads();
    if (tid == 0) {
        int off = 0, n1 = 0, n2 = 0;
        for (int e = 0; e < NEXP; ++e) {
            int cnt = cnt_s[e];
            ctrl[e] = cnt;
            ctrl[16 + e] = off; sOff[e] = off;
            int t128 = (cnt + 127) >> 7;
            for (int m = 0; m < t128; ++m)     ctrl[64 + n1++]  = (e << 16) | m;
            for (int m = 0; m < 2 * t128; ++m) ctrl[128 + n2++] = (e << 16) | m;
            off += t128 << 7;
        }
        ctrl[24] = off; ctrl[25] = n1; ctrl[26] = n2;
    }
    __syncthreads();
    for (int t = tid; t < NTOK; t += 256) {
        #pragma unroll
        for (int k = 0; k < 2; ++k) {
            int e = te[t * 2 + k];
            int s = atomicAdd(&cur[e], 1);
            int flat = sOff[e] + s;
            stok[flat] = t; tslot[t * 2 + k] = flat;
        }
    }
}

// ---------------- GEMM1: H = relu(Xg @ WfcT^T)^2, 128x128 tile, BK=64, XOR-swizzled LDS ----
__global__ __launch_bounds__(256) void k_gemm1(
    const unsigned short* __restrict__ xbf, const unsigned short* __restrict__ WfcT,
    const int* __restrict__ ctrl, const int* __restrict__ slot_tok,
    unsigned short* __restrict__ H)
{
    int bx = blockIdx.x;                      // grid = MAXT1*NT1 = 960
    int swz = (bx & 7) * (MAXT1 * NT1 / 8) + (bx >> 3);
    int nt = swz / MAXT1, tI = swz % MAXT1;
    if (tI >= ctrl[25]) return;
    int pk = ctrl[64 + tI];
    int e = pk >> 16, mt = pk & 0xffff;
    int base = ctrl[16 + e] + (mt << 7);

    __shared__ unsigned short sAB[2 * 128 * 64];   // sA | sB, reused as sC[128][128]
    unsigned short* sA = sAB;
    unsigned short* sB = sAB + 128 * 64;

    int tid = threadIdx.x, w = tid >> 6, lane = tid & 63;
    int wr = w >> 1, wc = w & 1;

    // source pre-swizzle: physical slot (lane&7) must hold global slot (lane&7)^(row&7),
    // row&7 = (lane>>3)&7 for the staging pattern
    int swsub = (((lane & 7) ^ ((lane >> 3) & 7)) << 3);
    const unsigned short* wfc = WfcT + ((size_t)e * DFF + nt * 128) * NEMBD;
    const unsigned short* aptr[4]; const unsigned short* bptr[4];
    #pragma unroll
    for (int i = 0; i < 4; ++i) {
        int r = i * 32 + w * 8 + (lane >> 3);
        aptr[i] = xbf + (size_t)slot_tok[base + r] * NEMBD + swsub;
        bptr[i] = wfc + (size_t)r * NEMBD + swsub;
    }

    f32x4 acc[4][4];
    #pragma unroll
    for (int i = 0; i < 4; ++i)
        #pragma unroll
        for (int j = 0; j < 4; ++j) acc[i][j] = (f32x4){0.f, 0.f, 0.f, 0.f};

    int rsw = (lane & 7) << 3;   // read-side XOR: (row&7)<<3, row&7 == lane&7
    for (int kk = 0; kk < NEMBD; kk += 64) {
        #pragma unroll
        for (int i = 0; i < 4; ++i) {
            gload16(aptr[i] + kk, &sA[(i * 256 + w * 64) * 8]);
            gload16(bptr[i] + kk, &sB[(i * 256 + w * 64) * 8]);
        }
        __syncthreads();
        #pragma unroll
        for (int kh = 0; kh < 2; ++kh) {
            int c = (kh * 32 + ((lane >> 4) << 3)) ^ rsw;
            short8v af[4], bfv[4];
            #pragma unroll
            for (int m = 0; m < 4; ++m)
                af[m] = *(const short8v*)&sA[(wr * 64 + m * 16 + (lane & 15)) * 64 + c];
            #pragma unroll
            for (int n = 0; n < 4; ++n)
                bfv[n] = *(const short8v*)&sB[(wc * 64 + n * 16 + (lane & 15)) * 64 + c];
            #pragma unroll
            for (int m = 0; m < 4; ++m)
                #pragma unroll
                for (int n = 0; n < 4; ++n)
                    acc[m][n] = __builtin_amdgcn_mfma_f32_16x16x32_bf16(af[m], bfv[n], acc[m][n], 0, 0, 0);
        }
        __syncthreads();
    }

    // epilogue: relu^2 -> bf16, repack via LDS for 16B coalesced stores
    unsigned short* sC = sAB;   // [128][128]
    #pragma unroll
    for (int m = 0; m < 4; ++m)
        #pragma unroll
        for (int n = 0; n < 4; ++n) {
            int col = wc * 64 + n * 16 + (lane & 15);
            #pragma unroll
            for (int i = 0; i < 4; ++i) {
                int row = wr * 64 + m * 16 + (lane >> 4) * 4 + i;
                float v = acc[m][n][i];
                v = v > 0.f ? v * v : 0.f;
                sC[row * 128 + col] = f2bf(v);
            }
        }
    __syncthreads();
    #pragma unroll
    for (int it = 0; it < 8; ++it) {
        int idx = tid + it * 256;
        int row = idx >> 4, j = idx & 15;
        *(int4v*)&H[(size_t)(base + row) * DFF + nt * 128 + j * 8] =
            *(const int4v*)&sC[row * 128 + j * 8];
    }
}

// ---------------- GEMM2: obuf[slot] = H @ WpT^T, 64x128 tile, BK=64, XOR-swizzled LDS ----
__global__ __launch_bounds__(256) void k_gemm2(
    const unsigned short* __restrict__ H, const unsigned short* __restrict__ WpT,
    const int* __restrict__ ctrl, float* __restrict__ obuf)
{
    int bx = blockIdx.x;                      // grid = MAXT2*NT2 = 480
    int swz = (bx & 7) * (MAXT2 * NT2 / 8) + (bx >> 3);
    int nt = swz / MAXT2, tI = swz % MAXT2;
    if (tI >= ctrl[26]) return;
    int pk = ctrl[128 + tI];
    int e = pk >> 16, mt = pk & 0xffff;
    int base = ctrl[16 + e] + (mt << 6);

    __shared__ unsigned short sA[64 * 64];    // 8 KB
    __shared__ unsigned short sB[128 * 64];   // 16 KB

    int tid = threadIdx.x, w = tid >> 6, lane = tid & 63;
    int wr = w >> 1, wc = w & 1;

    int swsub = (((lane & 7) ^ ((lane >> 3) & 7)) << 3);
    const unsigned short* wp = WpT + ((size_t)e * NEMBD + nt * 128) * DFF;
    const unsigned short* aptr[2]; const unsigned short* bptr[4];
    #pragma unroll
    for (int i = 0; i < 2; ++i) {
        int r = i * 32 + w * 8 + (lane >> 3);
        aptr[i] = H + (size_t)(base + r) * DFF + swsub;
    }
    #pragma unroll
    for (int i = 0; i < 4; ++i) {
        int r = i * 32 + w * 8 + (lane >> 3);
        bptr[i] = wp + (size_t)r * DFF + swsub;
    }

    f32x4 acc[2][4];
    #pragma unroll
    for (int i = 0; i < 2; ++i)
        #pragma unroll
        for (int j = 0; j < 4; ++j) acc[i][j] = (f32x4){0.f, 0.f, 0.f, 0.f};

    int rsw = (lane & 7) << 3;
    for (int kk = 0; kk < DFF; kk += 64) {
        #pragma unroll
        for (int i = 0; i < 2; ++i)
            gload16(aptr[i] + kk, &sA[(i * 256 + w * 64) * 8]);
        #pragma unroll
        for (int i = 0; i < 4; ++i)
            gload16(bptr[i] + kk, &sB[(i * 256 + w * 64) * 8]);
        __syncthreads();
        #pragma unroll
        for (int kh = 0; kh < 2; ++kh) {
            int c = (kh * 32 + ((lane >> 4) << 3)) ^ rsw;
            short8v af[2], bfv[4];
            #pragma unroll
            for (int m = 0; m < 2; ++m)
                af[m] = *(const short8v*)&sA[(wr * 32 + m * 16 + (lane & 15)) * 64 + c];
            #pragma unroll
            for (int n = 0; n < 4; ++n)
                bfv[n] = *(const short8v*)&sB[(wc * 64 + n * 16 + (lane & 15)) * 64 + c];
            #pragma unroll
            for (int m = 0; m < 2; ++m)
                #pragma unroll
                for (int n = 0; n < 4; ++n)
                    acc[m][n] = __builtin_amdgcn_mfma_f32_16x16x32_bf16(af[m], bfv[n], acc[m][n], 0, 0, 0);
        }
        __syncthreads();
    }

    #pragma unroll
    for (int m = 0; m < 2; ++m)
        #pragma unroll
        for (int n = 0; n < 4; ++n) {
            int col = nt * 128 + wc * 64 + n * 16 + (lane & 15);
            #pragma unroll
            for (int i = 0; i < 4; ++i) {
                int row = wr * 32 + m * 16 + (lane >> 4) * 4 + i;
                obuf[(size_t)(base + row) * NEMBD + col] = acc[m][n][i];
            }
        }
}

// ---------------- finish: combine (blocks 0..511) + aux loss (block 512) ----------------
__global__ __launch_bounds__(256) void k_finish(
    const float* __restrict__ obuf, const int* __restrict__ tslot,
    const float* __restrict__ tw, const float* __restrict__ gates,
    const float* __restrict__ kl_tok, const int* __restrict__ ctrl,
    float* __restrict__ out)
{
    int tid = threadIdx.x;
    if (blockIdx.x == 512) {
        __shared__ float sred[256];
        float p[NEXP]; float kls = 0.f;
        #pragma unroll
        for (int e = 0; e < NEXP; ++e) p[e] = 0.f;
        for (int t = tid; t < NTOK; t += 256) {
            #pragma unroll
            for (int e = 0; e < NEXP; ++e) p[e] += gates[t * NEXP + e];
            kls += kl_tok[t];
        }
        float Ps[NEXP];
        for (int e = 0; e < NEXP; ++e) {
            sred[tid] = p[e]; __syncthreads();
            for (int s = 128; s; s >>= 1) { if (tid < s) sred[tid] += sred[tid + s]; __syncthreads(); }
            if (tid == 0) Ps[e] = sred[0];
            __syncthreads();
        }
        sred[tid] = kls; __syncthreads();
        for (int s = 128; s; s >>= 1) { if (tid < s) sred[tid] += sred[tid + s]; __syncthreads(); }
        if (tid == 0) {
            float kl_mean = sred[0] / (float)NTOK;
            float lb = 0.f;
            for (int e = 0; e < NEXP; ++e)
                lb += ((float)ctrl[e] / (float)(NTOK * 2)) * (Ps[e] / (float)NTOK);
            lb *= (float)NEXP * 0.01f;
            out[(size_t)NTOK * NEMBD] = lb + kl_mean;
        }
        return;
    }
    int wave = tid >> 6, lane = tid & 63;
    int t = blockIdx.x * 4 + wave;
    int s0 = tslot[t * 2], s1 = tslot[t * 2 + 1];
    float g0 = tw[t * 2], g1 = tw[t * 2 + 1];
    const float4* r0 = (const float4*)(obuf + (size_t)s0 * NEMBD);
    const float4* r1 = (const float4*)(obuf + (size_t)s1 * NEMBD);
    float4* o4 = (float4*)(out + (size_t)t * NEMBD);
    #pragma unroll
    for (int j = 0; j < 3; ++j) {
        int c = j * 64 + lane;
        float4 a = r0[c], b = r1[c];
        float4 o;
        o.x = g0 * a.x + g1 * b.x; o.y = g0 * a.y + g1 * b.y;
        o.z = g0 * a.z + g1 * b.z; o.w = g0 * a.w + g1 * b.w;
        o4[c] = o;
    }
}

extern "C" void kernel_launch(void* const* d_in, const int* in_sizes, int n_in,
                              void* d_out, int out_size, void* d_ws, size_t ws_size,
                              hipStream_t stream) {
    const float* x   = (const float*)d_in[0];
    const float* WgP = (const float*)d_in[1];
    const float* WgQ = (const float*)d_in[2];
    const float* Wfc = (const float*)d_in[3];
    const float* Wpj = (const float*)d_in[4];
    float* out = (float*)d_out;

    char* ws = (char*)d_ws;
    unsigned short* xbf  = (unsigned short*)(ws + WS_XBF);
    float* gates = (float*)(ws + WS_GATES);
    int*   te    = (int*)(ws + WS_TE);
    float* tw    = (float*)(ws + WS_TW);
    float* klt   = (float*)(ws + WS_KL);
    int*   ctrl  = (int*)(ws + WS_CTRL);
    int*   stok  = (int*)(ws + WS_STOK);
    int*   tslot = (int*)(ws + WS_TSLOT);
    unsigned short* WfcT = (unsigned short*)(ws + WS_WFCT);
    unsigned short* WpT  = (unsigned short*)(ws + WS_WPT);
    unsigned short* H    = (unsigned short*)(ws + WS_H);
    float* obuf  = (float*)(ws + WS_OBUF);   // aliases WfcT (dead after gemm1)

    k_front<<<NTRB + 512, 256, 0, stream>>>(
        x, WgP, WgQ, Wfc, Wpj, WfcT, WpT, xbf, gates, te, tw, klt);
    k_sched<<<1, 256, 0, stream>>>(te, ctrl, stok, tslot);
    k_gemm1<<<MAXT1 * NT1, 256, 0, stream>>>(xbf, WfcT, ctrl, stok, H);
    k_gemm2<<<MAXT2 * NT2, 256, 0, stream>>>(H, WpT, ctrl, obuf);
    k_finish<<<513, 256, 0, stream>>>(obuf, tslot, tw, gates, klt, ctrl, out);
}

// Round 8
// 158.601 us; speedup vs baseline: 1.8193x; 1.0097x over previous
//
#include <hip/hip_runtime.h>
#include <hip/hip_bf16.h>

typedef __attribute__((ext_vector_type(8))) short short8v;   // 8 bf16
typedef __attribute__((ext_vector_type(4))) float f32x4;
typedef __attribute__((ext_vector_type(4))) int int4v;

#define NTOK  2048
#define NEMBD 768
#define DFF   3072
#define NEXP  8
#define MAXSLOT 5120          // 128-aligned per-expert regions, sum <= 5120
#define NT1 24                // DFF/128
#define NT2 6                 // NEMBD/128
#define MAXT1 40              // max 128-row tiles
#define MAXT2 80              // max 64-row tiles

// ---- workspace layout (bytes) ----
#define WS_XBF   0                                   // ushort [2048][768]
#define WS_GATES (WS_XBF + (size_t)NTOK*NEMBD*2)     // float  [2048][8]
#define WS_TE    (WS_GATES + NTOK*8*4)               // int    [2048][2]
#define WS_TW    (WS_TE + NTOK*2*4)                  // float  [2048][2]
#define WS_KL    (WS_TW + NTOK*2*4)                  // float  [2048]
#define WS_CTRL  (WS_KL + NTOK*4)                    // int[512]
#define WS_STOK  (WS_CTRL + 2048)                    // int    [MAXSLOT]
#define WS_TSLOT (WS_STOK + MAXSLOT*4)               // int    [2048][2]
#define WS_WFCT  (WS_TSLOT + NTOK*2*4)               // ushort [8][3072][768]  (obuf aliases this)
#define WS_WPT   (WS_WFCT + (size_t)NEXP*DFF*NEMBD*2)// ushort [8][768][3072]
#define WS_H     (WS_WPT + (size_t)NEXP*NEMBD*DFF*2) // ushort [MAXSLOT][3072]
#define WS_OBUF  WS_WFCT                             // float [MAXSLOT][768] aliases WfcT (dead after gemm1)

__device__ __forceinline__ unsigned short f2bf(float f) {
    union { float f; unsigned u; } v; v.f = f;
    unsigned r = v.u + 0x7fffu + ((v.u >> 16) & 1u);   // RNE
    return (unsigned short)(r >> 16);
}

__device__ __forceinline__ void gload16(const void* g, void* l) {
    __builtin_amdgcn_global_load_lds(
        (const __attribute__((address_space(1))) void*)g,
        (__attribute__((address_space(3))) void*)l, 16, 0, 0);
}

// ---- shared transpose tile body: in [E][R][C] f32 -> out [E][C][R] bf16 ----
// tile: 256 k-rows x 64 n-cols; LDS [n=64][slot=32] x 8 bf16, slot XOR; b128 both phases
__device__ __forceinline__ void transpose_tile(
    const float* __restrict__ in, unsigned short* __restrict__ out,
    int R, int C, int tilesC, int tb, unsigned short* sT, int tid)
{
    int e = tb / 144, rem = tb % 144;
    int rt = rem / tilesC, ct = rem % tilesC;
    int ng = tid & 7, kg = tid >> 3;
    const float* src = in + ((size_t)e * R + rt * 256 + kg * 8) * C + ct * 64 + ng * 8;
    unsigned short cb[8][8];
    #pragma unroll
    for (int i = 0; i < 8; ++i) {
        float4 a = *(const float4*)&src[(size_t)i * C];
        float4 b = *(const float4*)&src[(size_t)i * C + 4];
        cb[0][i] = f2bf(a.x); cb[1][i] = f2bf(a.y); cb[2][i] = f2bf(a.z); cb[3][i] = f2bf(a.w);
        cb[4][i] = f2bf(b.x); cb[5][i] = f2bf(b.y); cb[6][i] = f2bf(b.z); cb[7][i] = f2bf(b.w);
    }
    #pragma unroll
    for (int j = 0; j < 8; ++j) {
        int n = ng * 8 + j;
        int sl = kg ^ j;
        *(int4v*)&sT[((size_t)n * 32 + sl) * 8] = *(const int4v*)&cb[j][0];
    }
    __syncthreads();
    unsigned short* dstp = out + ((size_t)e * C + ct * 64) * R + rt * 256;
    int n2 = tid >> 2, cs = tid & 3;
    #pragma unroll
    for (int i = 0; i < 8; ++i) {
        int s = cs * 8 + i;
        int sl = s ^ (n2 & 7);
        *(int4v*)&dstp[(size_t)n2 * R + s * 8] = *(const int4v*)&sT[((size_t)n2 * 32 + sl) * 8];
    }
}

// ---------------- kernel A: router (blocks 0..511) + Wfc transpose (512..1663) ----------------
__global__ __launch_bounds__(256) void k_frontA(
    const float* __restrict__ x, const float* __restrict__ WgP, const float* __restrict__ WgQ,
    const float* __restrict__ Wfc, unsigned short* __restrict__ WfcT,
    unsigned short* __restrict__ xbf, float* __restrict__ gates,
    int* __restrict__ te, float* __restrict__ tw, float* __restrict__ kl_tok)
{
    __shared__ unsigned short sT[64 * 32 * 8];   // 32 KB
    int tid = threadIdx.x;
    int bid = blockIdx.x;
    if (bid >= 512) {
        transpose_tile(Wfc, WfcT, NEMBD, DFF, 48, bid - 512, sT, tid);
        return;
    }
    // -------- router: one wave per token, no global atomics --------
    int rb = bid;   // 0..511
    int wave = tid >> 6, lane = tid & 63;
    int t = rb * 4 + wave;
    int b = t >> 10, l = t & 1023;
    int lf = l + 2; if (lf > 1023) lf = 1023;           // lookforward pad-with-last
    const float* xr = x + (size_t)t * NEMBD;
    const float* xf = x + (size_t)((b << 10) + lf) * NEMBD;
    int e = lane & 7, kg = lane >> 3;

    float accP = 0.f, accQ = 0.f;
    #pragma unroll 8
    for (int i = 0; i < 96; ++i) {
        int k = kg + 8 * i;
        accP += xr[k] * WgP[k * NEXP + e];
        accQ += xf[k] * WgQ[k * NEXP + e];
    }
    #pragma unroll
    for (int off = 8; off < 64; off <<= 1) {
        accP += __shfl_xor(accP, off);
        accQ += __shfl_xor(accQ, off);
    }
    float mq = accQ, mp = accP;
    #pragma unroll
    for (int off = 1; off < 8; off <<= 1) {
        mq = fmaxf(mq, __shfl_xor(mq, off));
        mp = fmaxf(mp, __shfl_xor(mp, off));
    }
    float gq = __expf(accQ - mq), gp = __expf(accP - mp);
    float se = gq, sp = gp;
    #pragma unroll
    for (int off = 1; off < 8; off <<= 1) {
        se += __shfl_xor(se, off);
        sp += __shfl_xor(sp, off);
    }
    float v0 = gq; int e0 = e;
    #pragma unroll
    for (int off = 1; off < 8; off <<= 1) {
        float ov = __shfl_xor(v0, off); int oe = __shfl_xor(e0, off);
        if (ov > v0 || (ov == v0 && oe < e0)) { v0 = ov; e0 = oe; }
    }
    float vx = (e == e0) ? -1.f : gq;
    float v1 = vx; int e1 = e;
    #pragma unroll
    for (int off = 1; off < 8; off <<= 1) {
        float ov = __shfl_xor(v1, off); int oe = __shfl_xor(e1, off);
        if (ov > v1 || (ov == v1 && oe < e1)) { v1 = ov; e1 = oe; }
    }
    float lq = (accQ - mq) - logf(se);
    float lp = (accP - mp) - logf(sp);
    float kl = __expf(lq) * (lq - lp);
    #pragma unroll
    for (int off = 1; off < 8; off <<= 1) kl += __shfl_xor(kl, off);

    if (lane < 8) gates[t * NEXP + e] = gq / se;
    if (lane == 0) {
        float s2 = v0 + v1;
        te[t * 2] = e0; te[t * 2 + 1] = e1;
        tw[t * 2] = v0 / s2; tw[t * 2 + 1] = v1 / s2;
        kl_tok[t] = kl;
    }
    // x -> bf16 for this router block's 4 token rows
    const float4* xs4 = (const float4*)(x + (size_t)rb * 4 * NEMBD);
    ushort4* xd4 = (ushort4*)(xbf + (size_t)rb * 4 * NEMBD);
    for (int i = tid; i < 4 * NEMBD / 4; i += 256) {
        float4 v = xs4[i];
        ushort4 o;
        o.x = f2bf(v.x); o.y = f2bf(v.y); o.z = f2bf(v.z); o.w = f2bf(v.w);
        xd4[i] = o;
    }
}

// ---------------- sched: histogram + offsets + tile tables + slot lists (1 block) ---------
// ctrl: [0..7] counts, [16..23] expert base, [24] total, [25] nt1, [26] nt2,
//       [64..103] t1 (e<<16|mt), [128..207] t2
__global__ __launch_bounds__(256) void k_sched(
    const int* __restrict__ te, int* __restrict__ ctrl,
    int* __restrict__ stok, int* __restrict__ tslot)
{
    __shared__ int cur[NEXP];
    __shared__ int cnt_s[NEXP];
    __shared__ int sOff[NEXP];
    int tid = threadIdx.x, lane = tid & 63;
    if (tid < NEXP) { cur[tid] = 0; cnt_s[tid] = 0; }
    for (int i = tid; i < MAXSLOT; i += 256) stok[i] = 0;
    __syncthreads();
    int cc[NEXP];
    #pragma unroll
    for (int e = 0; e < NEXP; ++e) cc[e] = 0;
    for (int i = tid; i < NTOK * 2; i += 256) {
        int e = te[i];
        #pragma unroll
        for (int q = 0; q < NEXP; ++q) cc[q] += (e == q) ? 1 : 0;
    }
    #pragma unroll
    for (int e = 0; e < NEXP; ++e) {
        int v = cc[e];
        #pragma unroll
        for (int off = 32; off; off >>= 1) v += __shfl_xor(v, off);
        if (lane == 0) atomicAdd(&cnt_s[e], v);
    }
    __syncthreads();
    if (tid == 0) {
        int off = 0, n1 = 0, n2 = 0;
        for (int e = 0; e < NEXP; ++e) {
            int cnt = cnt_s[e];
            ctrl[e] = cnt;
            ctrl[16 + e] = off; sOff[e] = off;
            int t128 = (cnt + 127) >> 7;
            for (int m = 0; m < t128; ++m)     ctrl[64 + n1++]  = (e << 16) | m;
            for (int m = 0; m < 2 * t128; ++m) ctrl[128 + n2++] = (e << 16) | m;
            off += t128 << 7;
        }
        ctrl[24] = off; ctrl[25] = n1; ctrl[26] = n2;
    }
    __syncthreads();
    for (int t = tid; t < NTOK; t += 256) {
        #pragma unroll
        for (int k = 0; k < 2; ++k) {
            int e = te[t * 2 + k];
            int s = atomicAdd(&cur[e], 1);
            int flat = sOff[e] + s;
            stok[flat] = t; tslot[t * 2 + k] = flat;
        }
    }
}

// ---------------- kernel B: gemm1 (blocks 0..959) + Wp transpose (960..2111) ----------------
// GEMM1: H = relu(Xg @ WfcT^T)^2, 128x128 tile, BK=64, XOR-swizzled LDS
__global__ __launch_bounds__(256) void k_midB(
    const unsigned short* __restrict__ xbf, const unsigned short* __restrict__ WfcT,
    const float* __restrict__ Wpj, unsigned short* __restrict__ WpT,
    const int* __restrict__ ctrl, const int* __restrict__ slot_tok,
    unsigned short* __restrict__ H)
{
    __shared__ unsigned short sAB[2 * 128 * 64];   // 32 KB: gemm sA|sB / sC; transpose sT
    int tid = threadIdx.x;
    int bid = blockIdx.x;
    if (bid >= 960) {
        transpose_tile(Wpj, WpT, DFF, NEMBD, 12, bid - 960, sAB, tid);
        return;
    }
    int bx = bid;                             // gemm1: 960 blocks
    int swz = (bx & 7) * (MAXT1 * NT1 / 8) + (bx >> 3);
    int nt = swz / MAXT1, tI = swz % MAXT1;
    if (tI >= ctrl[25]) return;
    int pk = ctrl[64 + tI];
    int e = pk >> 16, mt = pk & 0xffff;
    int base = ctrl[16 + e] + (mt << 7);

    unsigned short* sA = sAB;
    unsigned short* sB = sAB + 128 * 64;

    int w = tid >> 6, lane = tid & 63;
    int wr = w >> 1, wc = w & 1;

    int swsub = (((lane & 7) ^ ((lane >> 3) & 7)) << 3);
    const unsigned short* wfc = WfcT + ((size_t)e * DFF + nt * 128) * NEMBD;
    const unsigned short* aptr[4]; const unsigned short* bptr[4];
    #pragma unroll
    for (int i = 0; i < 4; ++i) {
        int r = i * 32 + w * 8 + (lane >> 3);
        aptr[i] = xbf + (size_t)slot_tok[base + r] * NEMBD + swsub;
        bptr[i] = wfc + (size_t)r * NEMBD + swsub;
    }

    f32x4 acc[4][4];
    #pragma unroll
    for (int i = 0; i < 4; ++i)
        #pragma unroll
        for (int j = 0; j < 4; ++j) acc[i][j] = (f32x4){0.f, 0.f, 0.f, 0.f};

    int rsw = (lane & 7) << 3;
    for (int kk = 0; kk < NEMBD; kk += 64) {
        #pragma unroll
        for (int i = 0; i < 4; ++i) {
            gload16(aptr[i] + kk, &sA[(i * 256 + w * 64) * 8]);
            gload16(bptr[i] + kk, &sB[(i * 256 + w * 64) * 8]);
        }
        __syncthreads();
        #pragma unroll
        for (int kh = 0; kh < 2; ++kh) {
            int c = (kh * 32 + ((lane >> 4) << 3)) ^ rsw;
            short8v af[4], bfv[4];
            #pragma unroll
            for (int m = 0; m < 4; ++m)
                af[m] = *(const short8v*)&sA[(wr * 64 + m * 16 + (lane & 15)) * 64 + c];
            #pragma unroll
            for (int n = 0; n < 4; ++n)
                bfv[n] = *(const short8v*)&sB[(wc * 64 + n * 16 + (lane & 15)) * 64 + c];
            #pragma unroll
            for (int m = 0; m < 4; ++m)
                #pragma unroll
                for (int n = 0; n < 4; ++n)
                    acc[m][n] = __builtin_amdgcn_mfma_f32_16x16x32_bf16(af[m], bfv[n], acc[m][n], 0, 0, 0);
        }
        __syncthreads();
    }

    unsigned short* sC = sAB;   // [128][128]
    #pragma unroll
    for (int m = 0; m < 4; ++m)
        #pragma unroll
        for (int n = 0; n < 4; ++n) {
            int col = wc * 64 + n * 16 + (lane & 15);
            #pragma unroll
            for (int i = 0; i < 4; ++i) {
                int row = wr * 64 + m * 16 + (lane >> 4) * 4 + i;
                float v = acc[m][n][i];
                v = v > 0.f ? v * v : 0.f;
                sC[row * 128 + col] = f2bf(v);
            }
        }
    __syncthreads();
    #pragma unroll
    for (int it = 0; it < 8; ++it) {
        int idx = tid + it * 256;
        int row = idx >> 4, j = idx & 15;
        *(int4v*)&H[(size_t)(base + row) * DFF + nt * 128 + j * 8] =
            *(const int4v*)&sC[row * 128 + j * 8];
    }
}

// ---------------- GEMM2: obuf[slot] = H @ WpT^T, 64x128 tile, BK=64, XOR-swizzled LDS ----
__global__ __launch_bounds__(256) void k_gemm2(
    const unsigned short* __restrict__ H, const unsigned short* __restrict__ WpT,
    const int* __restrict__ ctrl, float* __restrict__ obuf)
{
    int bx = blockIdx.x;                      // grid = MAXT2*NT2 = 480
    int swz = (bx & 7) * (MAXT2 * NT2 / 8) + (bx >> 3);
    int nt = swz / MAXT2, tI = swz % MAXT2;
    if (tI >= ctrl[26]) return;
    int pk = ctrl[128 + tI];
    int e = pk >> 16, mt = pk & 0xffff;
    int base = ctrl[16 + e] + (mt << 6);

    __shared__ unsigned short sA[64 * 64];    // 8 KB
    __shared__ unsigned short sB[128 * 64];   // 16 KB

    int tid = threadIdx.x, w = tid >> 6, lane = tid & 63;
    int wr = w >> 1, wc = w & 1;

    int swsub = (((lane & 7) ^ ((lane >> 3) & 7)) << 3);
    const unsigned short* wp = WpT + ((size_t)e * NEMBD + nt * 128) * DFF;
    const unsigned short* aptr[2]; const unsigned short* bptr[4];
    #pragma unroll
    for (int i = 0; i < 2; ++i) {
        int r = i * 32 + w * 8 + (lane >> 3);
        aptr[i] = H + (size_t)(base + r) * DFF + swsub;
    }
    #pragma unroll
    for (int i = 0; i < 4; ++i) {
        int r = i * 32 + w * 8 + (lane >> 3);
        bptr[i] = wp + (size_t)r * DFF + swsub;
    }

    f32x4 acc[2][4];
    #pragma unroll
    for (int i = 0; i < 2; ++i)
        #pragma unroll
        for (int j = 0; j < 4; ++j) acc[i][j] = (f32x4){0.f, 0.f, 0.f, 0.f};

    int rsw = (lane & 7) << 3;
    for (int kk = 0; kk < DFF; kk += 64) {
        #pragma unroll
        for (int i = 0; i < 2; ++i)
            gload16(aptr[i] + kk, &sA[(i * 256 + w * 64) * 8]);
        #pragma unroll
        for (int i = 0; i < 4; ++i)
            gload16(bptr[i] + kk, &sB[(i * 256 + w * 64) * 8]);
        __syncthreads();
        #pragma unroll
        for (int kh = 0; kh < 2; ++kh) {
            int c = (kh * 32 + ((lane >> 4) << 3)) ^ rsw;
            short8v af[2], bfv[4];
            #pragma unroll
            for (int m = 0; m < 2; ++m)
                af[m] = *(const short8v*)&sA[(wr * 32 + m * 16 + (lane & 15)) * 64 + c];
            #pragma unroll
            for (int n = 0; n < 4; ++n)
                bfv[n] = *(const short8v*)&sB[(wc * 64 + n * 16 + (lane & 15)) * 64 + c];
            #pragma unroll
            for (int m = 0; m < 2; ++m)
                #pragma unroll
                for (int n = 0; n < 4; ++n)
                    acc[m][n] = __builtin_amdgcn_mfma_f32_16x16x32_bf16(af[m], bfv[n], acc[m][n], 0, 0, 0);
        }
        __syncthreads();
    }

    #pragma unroll
    for (int m = 0; m < 2; ++m)
        #pragma unroll
        for (int n = 0; n < 4; ++n) {
            int col = nt * 128 + wc * 64 + n * 16 + (lane & 15);
            #pragma unroll
            for (int i = 0; i < 4; ++i) {
                int row = wr * 32 + m * 16 + (lane >> 4) * 4 + i;
                obuf[(size_t)(base + row) * NEMBD + col] = acc[m][n][i];
            }
        }
}

// ---------------- finish: combine (blocks 0..511) + aux loss (block 512) ----------------
__global__ __launch_bounds__(256) void k_finish(
    const float* __restrict__ obuf, const int* __restrict__ tslot,
    const float* __restrict__ tw, const float* __restrict__ gates,
    const float* __restrict__ kl_tok, const int* __restrict__ ctrl,
    float* __restrict__ out)
{
    int tid = threadIdx.x;
    if (blockIdx.x == 512) {
        __shared__ float sred[256];
        float p[NEXP]; float kls = 0.f;
        #pragma unroll
        for (int e = 0; e < NEXP; ++e) p[e] = 0.f;
        for (int t = tid; t < NTOK; t += 256) {
            #pragma unroll
            for (int e = 0; e < NEXP; ++e) p[e] += gates[t * NEXP + e];
            kls += kl_tok[t];
        }
        float Ps[NEXP];
        for (int e = 0; e < NEXP; ++e) {
            sred[tid] = p[e]; __syncthreads();
            for (int s = 128; s; s >>= 1) { if (tid < s) sred[tid] += sred[tid + s]; __syncthreads(); }
            if (tid == 0) Ps[e] = sred[0];
            __syncthreads();
        }
        sred[tid] = kls; __syncthreads();
        for (int s = 128; s; s >>= 1) { if (tid < s) sred[tid] += sred[tid + s]; __syncthreads(); }
        if (tid == 0) {
            float kl_mean = sred[0] / (float)NTOK;
            float lb = 0.f;
            for (int e = 0; e < NEXP; ++e)
                lb += ((float)ctrl[e] / (float)(NTOK * 2)) * (Ps[e] / (float)NTOK);
            lb *= (float)NEXP * 0.01f;
            out[(size_t)NTOK * NEMBD] = lb + kl_mean;
        }
        return;
    }
    int wave = tid >> 6, lane = tid & 63;
    int t = blockIdx.x * 4 + wave;
    int s0 = tslot[t * 2], s1 = tslot[t * 2 + 1];
    float g0 = tw[t * 2], g1 = tw[t * 2 + 1];
    const float4* r0 = (const float4*)(obuf + (size_t)s0 * NEMBD);
    const float4* r1 = (const float4*)(obuf + (size_t)s1 * NEMBD);
    float4* o4 = (float4*)(out + (size_t)t * NEMBD);
    #pragma unroll
    for (int j = 0; j < 3; ++j) {
        int c = j * 64 + lane;
        float4 a = r0[c], b = r1[c];
        float4 o;
        o.x = g0 * a.x + g1 * b.x; o.y = g0 * a.y + g1 * b.y;
        o.z = g0 * a.z + g1 * b.z; o.w = g0 * a.w + g1 * b.w;
        o4[c] = o;
    }
}

extern "C" void kernel_launch(void* const* d_in, const int* in_sizes, int n_in,
                              void* d_out, int out_size, void* d_ws, size_t ws_size,
                              hipStream_t stream) {
    const float* x   = (const float*)d_in[0];
    const float* WgP = (const float*)d_in[1];
    const float* WgQ = (const float*)d_in[2];
    const float* Wfc = (const float*)d_in[3];
    const float* Wpj = (const float*)d_in[4];
    float* out = (float*)d_out;

    char* ws = (char*)d_ws;
    unsigned short* xbf  = (unsigned short*)(ws + WS_XBF);
    float* gates = (float*)(ws + WS_GATES);
    int*   te    = (int*)(ws + WS_TE);
    float* tw    = (float*)(ws + WS_TW);
    float* klt   = (float*)(ws + WS_KL);
    int*   ctrl  = (int*)(ws + WS_CTRL);
    int*   stok  = (int*)(ws + WS_STOK);
    int*   tslot = (int*)(ws + WS_TSLOT);
    unsigned short* WfcT = (unsigned short*)(ws + WS_WFCT);
    unsigned short* WpT  = (unsigned short*)(ws + WS_WPT);
    unsigned short* H    = (unsigned short*)(ws + WS_H);
    float* obuf  = (float*)(ws + WS_OBUF);   // aliases WfcT (dead after gemm1)

    k_frontA<<<512 + 1152, 256, 0, stream>>>(
        x, WgP, WgQ, Wfc, WfcT, xbf, gates, te, tw, klt);
    k_sched<<<1, 256, 0, stream>>>(te, ctrl, stok, tslot);
    k_midB<<<960 + 1152, 256, 0, stream>>>(xbf, WfcT, Wpj, WpT, ctrl, stok, H);
    k_gemm2<<<MAXT2 * NT2, 256, 0, stream>>>(H, WpT, ctrl, obuf);
    k_finish<<<513, 256, 0, stream>>>(obuf, tslot, tw, gates, klt, ctrl, out);
}